// Round 9
// baseline (483.943 us; speedup 1.0000x reference)
//
#include <hip/hip_runtime.h>
#include <hip/hip_bf16.h>

// Problem constants
constexpr int B      = 4;
constexpr int LQ     = 640;
constexpr int LIM    = 1296;
constexpr int LK     = LQ + LIM;   // 1936
constexpr int DM     = 768;
constexpr int NHEAD  = 12;
constexpr int DK     = 64;
constexpr int DFF    = 3072;
constexpr int MAXD   = 100;
constexpr int M_DOC  = B * LQ;     // 2560
constexpr int M_FULL = B * LK;     // 7744
constexpr size_t ML_CNT = (size_t)B * NHEAD * LQ;   // 30720 (m,l) rows per split

typedef __attribute__((ext_vector_type(8))) short bf16x8_t;   // 8 bf16 = 4 VGPRs
typedef __attribute__((ext_vector_type(4))) float f32x4_t;    // MFMA C/D

__device__ __forceinline__ float b2f(__hip_bfloat16 x) { return __bfloat162float(x); }

__device__ __forceinline__ float ldf(const void* p, size_t i, int f32flag) {
    return f32flag ? ((const float*)p)[i]
                   : b2f(((const __hip_bfloat16*)p)[i]);
}

// async global->LDS, 16 bytes per lane. LDS dest = wave-uniform base + lane*16.
__device__ __forceinline__ void gl_lds16(const void* g, void* l) {
    __builtin_amdgcn_global_load_lds(
        (const __attribute__((address_space(1))) unsigned int*)g,
        (__attribute__((address_space(3))) unsigned int*)l, 16, 0, 0);
}

// ---------------------------------------------------------------------------
// prep: dtype flag + convert concat(im, docqa) -> contiguous bf16 fullA.
// One 8-element chunk per thread (M_FULL*DM/8 = 743424 chunks).
// ---------------------------------------------------------------------------
__global__ __launch_bounds__(256)
void prep_conv_kernel(const void* __restrict__ g1, int* __restrict__ flagp,
                      const void* __restrict__ im, const void* __restrict__ docqa,
                      __hip_bfloat16* __restrict__ fullA)
{
    const bool f32 = ((*(const unsigned*)g1) & 0xFFFFu) == 0u;
    if (blockIdx.x == 0 && threadIdx.x == 0) *flagp = f32 ? 1 : 0;

    const int chunk = blockIdx.x * 256 + threadIdx.x;
    if (chunk >= M_FULL * (DM / 8)) return;
    const int row = chunk / (DM / 8);
    const int col = (chunk - row * (DM / 8)) * 8;
    const int b   = row / LK;
    const int l   = row - b * LK;
    const size_t srow = (l < LIM) ? ((size_t)(b * LIM + l)) * DM
                                  : ((size_t)(b * LQ + (l - LIM))) * DM;
    const void* src = (l < LIM) ? im : docqa;
    union { bf16x8_t v; __hip_bfloat16 h[8]; } pk;
    if (f32) {
        const float4* fp = (const float4*)((const float*)src + srow + col);
        float4 a = fp[0], c = fp[1];
        pk.h[0] = __float2bfloat16(a.x); pk.h[1] = __float2bfloat16(a.y);
        pk.h[2] = __float2bfloat16(a.z); pk.h[3] = __float2bfloat16(a.w);
        pk.h[4] = __float2bfloat16(c.x); pk.h[5] = __float2bfloat16(c.y);
        pk.h[6] = __float2bfloat16(c.z); pk.h[7] = __float2bfloat16(c.w);
    } else {
        pk.v = *(const bf16x8_t*)((const __hip_bfloat16*)src + srow + col);
    }
    *(bf16x8_t*)(fullA + (size_t)row * DM + col) = pk.v;
}

// ---------------------------------------------------------------------------
// Transpose 32x32 tile helper (K x N flagged -> N x K bf16).
// ---------------------------------------------------------------------------
__device__ __forceinline__ void wtrans_tile(const void* W, __hip_bfloat16* Wt,
                                            int f32, int K, int N, int n0, int k0,
                                            __hip_bfloat16 (*t)[33])
{
    const int tx = threadIdx.x & 31, ty = threadIdx.x >> 5;
#pragma unroll
    for (int j = 0; j < 4; ++j) {
        int k = ty + j * 8;
        t[k][tx] = __float2bfloat16(ldf(W, (size_t)(k0 + k) * N + n0 + tx, f32));
    }
    __syncthreads();
#pragma unroll
    for (int j = 0; j < 4; ++j) {
        int n = ty + j * 8;
        Wt[(size_t)(n0 + n) * K + k0 + tx] = t[tx][n];
    }
}

// Wq,Wk,Wv -> Wt3 (2304 x 768). 3*576 blocks.
__global__ __launch_bounds__(256)
void wtrans3_kernel(const void* __restrict__ Wq, const void* __restrict__ Wk,
                    const void* __restrict__ Wv, __hip_bfloat16* __restrict__ Wt3,
                    const int* __restrict__ flagp)
{
    __shared__ __hip_bfloat16 t[32][33];
    const int f32 = *flagp;
    const int wid = blockIdx.x / 576;
    const int tt  = blockIdx.x % 576;
    const void* W = (wid == 0) ? Wq : (wid == 1) ? Wk : Wv;
    wtrans_tile(W, Wt3 + (size_t)wid * DM * DM, f32, DM, DM,
                (tt % 24) * 32, (tt / 24) * 32, t);
}

// Wo -> WtO. 576 blocks.
__global__ __launch_bounds__(256)
void wtransO_kernel(const void* __restrict__ Wo, __hip_bfloat16* __restrict__ WtO,
                    const int* __restrict__ flagp)
{
    __shared__ __hip_bfloat16 t[32][33];
    const int f32 = *flagp;
    const int tt  = blockIdx.x;
    wtrans_tile(Wo, WtO, f32, DM, DM, (tt % 24) * 32, (tt / 24) * 32, t);
}

// W1 (768x3072) -> W1t, W2 (3072x768) -> W2t. 2*2304 blocks.
__global__ __launch_bounds__(256)
void wtransW_kernel(const void* __restrict__ W1, const void* __restrict__ W2,
                    __hip_bfloat16* __restrict__ W1t, __hip_bfloat16* __restrict__ W2t,
                    const int* __restrict__ flagp)
{
    __shared__ __hip_bfloat16 t[32][33];
    const int f32 = *flagp;
    int bx = blockIdx.x;
    const bool second = bx >= 2304;
    const void* W = second ? W2 : W1;
    __hip_bfloat16* dst = second ? W2t : W1t;
    const int K = second ? DFF : DM;
    const int N = second ? DM : DFF;
    const int tt = second ? bx - 2304 : bx;
    const int nt = N / 32;
    wtrans_tile(W, dst, f32, K, N, (tt % nt) * 32, (tt / nt) * 32, t);
}

// ---------------------------------------------------------------------------
// Fused QKV GEMM, pure m97 structure: A = fullA bf16 via global_load_lds.
// q (doc rows, *1/8) -> qout (d_out scratch); k row-major; V transposed
// per (b,h): vtb[((b*NHEAD+h)*DK + d) * LK + kk].
// ---------------------------------------------------------------------------
__global__ __launch_bounds__(256)
void qkv_gemm(const __hip_bfloat16* __restrict__ fullA,
              const __hip_bfloat16* __restrict__ Wt3,
              const void* __restrict__ bq,
              const void* __restrict__ bk,
              const void* __restrict__ bv,
              __hip_bfloat16* __restrict__ qout,
              __hip_bfloat16* __restrict__ kb,
              __hip_bfloat16* __restrict__ vtb,
              const int* __restrict__ flagp)
{
    __shared__ __hip_bfloat16 Als[128 * 32];
    __shared__ __hip_bfloat16 Bls[128 * 32];

    const int f32  = *flagp;
    const int tid  = threadIdx.x;
    const int lane = tid & 63;
    const int wave = tid >> 6;
    const int quad = lane >> 4;
    const int c16  = lane & 15;
    const int n0   = blockIdx.x * 128;
    const int m0   = blockIdx.y * 128;
    const int wm   = (wave >> 1) * 64;
    const int wn   = (wave & 1) * 64;
    constexpr int K = DM;

    f32x4_t acc[4][4] = {};

    for (int k0 = 0; k0 < K; k0 += 32) {
#pragma unroll
        for (int p = 0; p < 2; ++p) {
            const int lin = p * 64 + lane;
            int row = wave * 32 + (lin >> 2);
            int gr  = m0 + row; if (gr > M_FULL - 1) gr = M_FULL - 1;
            gl_lds16(fullA + (size_t)gr * K + k0 + (lin & 3) * 8,
                     Als + wave * 1024 + p * 512);
        }
#pragma unroll
        for (int p = 0; p < 2; ++p) {
            const int lin = p * 64 + lane;
            const int row = wave * 32 + (lin >> 2);
            gl_lds16(Wt3 + (size_t)(n0 + row) * K + k0 + (lin & 3) * 8,
                     Bls + wave * 1024 + p * 512);
        }
        __syncthreads();

        bf16x8_t af[4], bfr[4];
#pragma unroll
        for (int i = 0; i < 4; ++i)
            af[i] = *(const bf16x8_t*)(Als + (wm + i * 16 + c16) * 32 + quad * 8);
#pragma unroll
        for (int j = 0; j < 4; ++j)
            bfr[j] = *(const bf16x8_t*)(Bls + (wn + j * 16 + c16) * 32 + quad * 8);
#pragma unroll
        for (int i = 0; i < 4; ++i)
#pragma unroll
            for (int j = 0; j < 4; ++j)
                acc[i][j] = __builtin_amdgcn_mfma_f32_16x16x32_bf16(af[i], bfr[j], acc[i][j], 0, 0, 0);
        __syncthreads();
    }

    const int seg = n0 / DM;                 // 0=q 1=k 2=v
    const void* bptr = (seg == 0) ? bq : (seg == 1) ? bk : bv;
#pragma unroll
    for (int j = 0; j < 4; ++j) {
        const int col  = n0 + wn + j * 16 + c16;
        const int ncol = col - seg * DM;
        const float bj = ldf(bptr, ncol, f32);
        if (seg == 2) {
            // V transposed: vtb[((bb*NHEAD+h)*DK+d)*LK + kk]
            const int h = ncol >> 6, d = ncol & 63;
#pragma unroll
            for (int i = 0; i < 4; ++i) {
                const int rowb = m0 + wm + i * 16 + quad * 4;
                const int bb0  = rowb / LK;
                const int l0   = rowb - bb0 * LK;
                if (l0 + 3 < LK && rowb + 3 < M_FULL) {
                    union { ushort4 u4; __hip_bfloat16 hh[4]; } pk;
#pragma unroll
                    for (int r = 0; r < 4; ++r)
                        pk.hh[r] = __float2bfloat16(acc[i][j][r] + bj);
                    *(ushort4*)(vtb + ((size_t)((bb0 * NHEAD + h) * DK + d)) * LK + l0) = pk.u4;
                } else {
#pragma unroll
                    for (int r = 0; r < 4; ++r) {
                        const int row = rowb + r;
                        if (row < M_FULL) {
                            int bb = row / LK, l = row - bb * LK;
                            vtb[((size_t)((bb * NHEAD + h) * DK + d)) * LK + l] =
                                __float2bfloat16(acc[i][j][r] + bj);
                        }
                    }
                }
            }
        } else {
            const float scl = (seg == 0) ? 0.125f : 1.f;
#pragma unroll
            for (int i = 0; i < 4; ++i) {
                const int rowb = m0 + wm + i * 16 + quad * 4;
#pragma unroll
                for (int r = 0; r < 4; ++r) {
                    const int row = rowb + r;
                    if (row < M_FULL) {
                        __hip_bfloat16 hv = __float2bfloat16((acc[i][j][r] + bj) * scl);
                        if (seg == 1) kb[(size_t)row * DM + ncol] = hv;
                        else {
                            int bb = row / LK, l = row - bb * LK;
                            if (l >= LIM)
                                qout[(size_t)(bb * LQ + (l - LIM)) * DM + ncol] = hv;
                        }
                    }
                }
            }
        }
    }
}

// Standard MFMA GEMM (bias + relu) for FFN1.
__global__ __launch_bounds__(256)
void mfma_gemm_relu(const __hip_bfloat16* __restrict__ Abf,
                    const __hip_bfloat16* __restrict__ Wt,
                    const void* __restrict__ bias,
                    __hip_bfloat16* __restrict__ Cc,
                    const int* __restrict__ flagp,
                    int M, int N, int K)
{
    __shared__ __hip_bfloat16 Als[128 * 32];
    __shared__ __hip_bfloat16 Bls[128 * 32];

    const int f32  = *flagp;
    const int tid  = threadIdx.x;
    const int lane = tid & 63;
    const int wave = tid >> 6;
    const int quad = lane >> 4;
    const int c16  = lane & 15;
    const int n0   = blockIdx.x * 128;
    const int m0   = blockIdx.y * 128;
    const int wm   = (wave >> 1) * 64;
    const int wn   = (wave & 1) * 64;

    f32x4_t acc[4][4] = {};

    for (int k0 = 0; k0 < K; k0 += 32) {
#pragma unroll
        for (int p = 0; p < 2; ++p) {
            const int lin = p * 64 + lane;
            int row = wave * 32 + (lin >> 2);
            int gr  = m0 + row; if (gr > M - 1) gr = M - 1;
            gl_lds16(Abf + (size_t)gr * K + k0 + (lin & 3) * 8, Als + wave * 1024 + p * 512);
        }
#pragma unroll
        for (int p = 0; p < 2; ++p) {
            const int lin = p * 64 + lane;
            const int row = wave * 32 + (lin >> 2);
            gl_lds16(Wt + (size_t)(n0 + row) * K + k0 + (lin & 3) * 8,
                     Bls + wave * 1024 + p * 512);
        }
        __syncthreads();

        bf16x8_t af[4], bfr[4];
#pragma unroll
        for (int i = 0; i < 4; ++i)
            af[i] = *(const bf16x8_t*)(Als + (wm + i * 16 + c16) * 32 + quad * 8);
#pragma unroll
        for (int j = 0; j < 4; ++j)
            bfr[j] = *(const bf16x8_t*)(Bls + (wn + j * 16 + c16) * 32 + quad * 8);
#pragma unroll
        for (int i = 0; i < 4; ++i)
#pragma unroll
            for (int j = 0; j < 4; ++j)
                acc[i][j] = __builtin_amdgcn_mfma_f32_16x16x32_bf16(af[i], bfr[j], acc[i][j], 0, 0, 0);
        __syncthreads();
    }

#pragma unroll
    for (int j = 0; j < 4; ++j) {
        const int col = n0 + wn + j * 16 + c16;
        const float bj = ldf(bias, col, f32);
#pragma unroll
        for (int i = 0; i < 4; ++i) {
            const int rowb = m0 + wm + i * 16 + quad * 4;
#pragma unroll
            for (int r = 0; r < 4; ++r) {
                const int row = rowb + r;
                if (row < M) {
                    float v = fmaxf(acc[i][j][r] + bj, 0.f);
                    Cc[(size_t)row * N + col] = __float2bfloat16(v);
                }
            }
        }
    }
}

// Split-K MFMA GEMM: f32 atomic accumulate (dest pre-zeroed), grid z = chunk.
__global__ __launch_bounds__(256)
void sk_gemm(const __hip_bfloat16* __restrict__ Abf,
             const __hip_bfloat16* __restrict__ Wt,
             float* __restrict__ Cc,
             int M, int N, int K, int S)
{
    __shared__ __hip_bfloat16 Als[128 * 32];
    __shared__ __hip_bfloat16 Bls[128 * 32];

    const int tid  = threadIdx.x;
    const int lane = tid & 63;
    const int wave = tid >> 6;
    const int quad = lane >> 4;
    const int c16  = lane & 15;
    const int n0   = blockIdx.x * 128;
    const int m0   = blockIdx.y * 128;
    const int wm   = (wave >> 1) * 64;
    const int wn   = (wave & 1) * 64;
    const int kchunk = K / S;
    const int kbeg = blockIdx.z * kchunk;

    f32x4_t acc[4][4] = {};

    for (int k0 = kbeg; k0 < kbeg + kchunk; k0 += 32) {
#pragma unroll
        for (int p = 0; p < 2; ++p) {
            const int lin = p * 64 + lane;
            int row = wave * 32 + (lin >> 2);
            int gr  = m0 + row; if (gr > M - 1) gr = M - 1;
            gl_lds16(Abf + (size_t)gr * K + k0 + (lin & 3) * 8, Als + wave * 1024 + p * 512);
        }
#pragma unroll
        for (int p = 0; p < 2; ++p) {
            const int lin = p * 64 + lane;
            const int row = wave * 32 + (lin >> 2);
            gl_lds16(Wt + (size_t)(n0 + row) * K + k0 + (lin & 3) * 8,
                     Bls + wave * 1024 + p * 512);
        }
        __syncthreads();

        bf16x8_t af[4], bfr[4];
#pragma unroll
        for (int i = 0; i < 4; ++i)
            af[i] = *(const bf16x8_t*)(Als + (wm + i * 16 + c16) * 32 + quad * 8);
#pragma unroll
        for (int j = 0; j < 4; ++j)
            bfr[j] = *(const bf16x8_t*)(Bls + (wn + j * 16 + c16) * 32 + quad * 8);
#pragma unroll
        for (int i = 0; i < 4; ++i)
#pragma unroll
            for (int j = 0; j < 4; ++j)
                acc[i][j] = __builtin_amdgcn_mfma_f32_16x16x32_bf16(af[i], bfr[j], acc[i][j], 0, 0, 0);
        __syncthreads();
    }

#pragma unroll
    for (int j = 0; j < 4; ++j) {
        const int col = n0 + wn + j * 16 + c16;
#pragma unroll
        for (int i = 0; i < 4; ++i) {
            const int rowb = m0 + wm + i * 16 + quad * 4;
#pragma unroll
            for (int r = 0; r < 4; ++r) {
                const int row = rowb + r;
                if (row < M) atomicAdd(&Cc[(size_t)row * N + col], acc[i][j][r]);
            }
        }
    }
}

// ---------------------------------------------------------------------------
// MFMA flash attention, direct-global operand feed, K-split S=2.
// Grid (10, 12, B*2): b=z&3, s=z>>2. Coords selected inline from im/doc arrays.
// Writes unnormalized partial O (bf16) + per-(b,h,q) m,l.
// ---------------------------------------------------------------------------
__global__ __launch_bounds__(256)
void attn_part_kernel(const __hip_bfloat16* __restrict__ Qb,
                      const __hip_bfloat16* __restrict__ Kb,
                      const __hip_bfloat16* __restrict__ Vtb,
                      const int* __restrict__ dqx, const int* __restrict__ dqy,
                      const int* __restrict__ imx, const int* __restrict__ imy,
                      const void* __restrict__ bias_x,
                      const void* __restrict__ bias_y,
                      __hip_bfloat16* __restrict__ p0,
                      __hip_bfloat16* __restrict__ p1,
                      float* __restrict__ mlbase,
                      const int* __restrict__ flagp)
{
    constexpr int QT = 64, KT = 64;
    constexpr int QROW = 72;
    __shared__ __hip_bfloat16 Ps[QT * QROW];
    __shared__ float bxs[2 * MAXD + 1], bys[2 * MAXD + 1];

    const int f32  = *flagp;
    const int tid  = threadIdx.x;
    const int lane = tid & 63;
    const int wave = tid >> 6;
    const int quad = lane >> 4;
    const int c16  = lane & 15;
    const int h    = blockIdx.y;
    const int b    = blockIdx.z & 3;
    const int s    = blockIdx.z >> 2;
    const int q0   = blockIdx.x * QT;
    const int kbeg = s * 1024;
    const int kend = s ? LK : 1024;

    __hip_bfloat16* Op = s ? p1 : p0;
    float* mp = mlbase + (size_t)s * 2 * ML_CNT;
    float* lp = mp + ML_CNT;

    for (int i = tid; i < 2 * MAXD + 1; i += 256) {
        bxs[i] = ldf(bias_x, (size_t)i * NHEAD + h, f32);
        bys[i] = ldf(bias_y, (size_t)i * NHEAD + h, f32);
    }

    // Loop-invariant Q fragments + q coords (direct global)
    const __hip_bfloat16* qrow = Qb + ((size_t)(b * LQ + q0 + wave * 16 + c16)) * DM + h * DK;
    const bf16x8_t aq0 = *(const bf16x8_t*)(qrow + quad * 8);
    const bf16x8_t aq1 = *(const bf16x8_t*)(qrow + 32 + quad * 8);
    int qx[4], qy[4];
#pragma unroll
    for (int r = 0; r < 4; ++r) {
        const int qi = b * LQ + q0 + wave * 16 + quad * 4 + r;
        qx[r] = dqx[qi]; qy[r] = dqy[qi];
    }
    const __hip_bfloat16* vrow = Vtb + ((size_t)((b * NHEAD + h) * DK)) * LK;

    __syncthreads();   // bias tables visible

    f32x4_t O[4] = {};
    float m_r[4], l_r[4];
#pragma unroll
    for (int r = 0; r < 4; ++r) { m_r[r] = -1e30f; l_r[r] = 0.f; }

    for (int k0 = kbeg; k0 < kend; k0 += KT) {
        // ---- scores: direct-global K fragments ----
        f32x4_t S[4];
#pragma unroll
        for (int jn = 0; jn < 4; ++jn) {
            int krow = k0 + jn * 16 + c16; if (krow > LK - 1) krow = LK - 1;
            const __hip_bfloat16* kr = Kb + ((size_t)(b * LK + krow)) * DM + h * DK;
            bf16x8_t bk0 = *(const bf16x8_t*)(kr + quad * 8);
            bf16x8_t bk1 = *(const bf16x8_t*)(kr + 32 + quad * 8);
            f32x4_t acc = {0.f, 0.f, 0.f, 0.f};
            acc = __builtin_amdgcn_mfma_f32_16x16x32_bf16(aq0, bk0, acc, 0, 0, 0);
            acc = __builtin_amdgcn_mfma_f32_16x16x32_bf16(aq1, bk1, acc, 0, 0, 0);
            S[jn] = acc;
        }
        // ---- bias + tail mask (inline concat coord select) ----
#pragma unroll
        for (int jn = 0; jn < 4; ++jn) {
            const int kg = k0 + jn * 16 + c16;
            const bool ok = kg < LK;
            const int kgc = ok ? kg : LK - 1;
            const int kx = (kgc < LIM) ? imx[b * LIM + kgc] : dqx[b * LQ + kgc - LIM];
            const int ky = (kgc < LIM) ? imy[b * LIM + kgc] : dqy[b * LQ + kgc - LIM];
#pragma unroll
            for (int r = 0; r < 4; ++r) {
                int rx = min(max(qx[r] - kx, -MAXD), MAXD) + MAXD;
                int ry = min(max(qy[r] - ky, -MAXD), MAXD) + MAXD;
                float v = S[jn][r] + bxs[rx] + bys[ry];
                S[jn][r] = ok ? v : -1e30f;
            }
        }
        // ---- online softmax (registers + shfl over 16-lane row group) ----
        float alpha[4];
#pragma unroll
        for (int r = 0; r < 4; ++r) {
            float mx = fmaxf(fmaxf(S[0][r], S[1][r]), fmaxf(S[2][r], S[3][r]));
            mx = fmaxf(mx, __shfl_xor(mx, 1));
            mx = fmaxf(mx, __shfl_xor(mx, 2));
            mx = fmaxf(mx, __shfl_xor(mx, 4));
            mx = fmaxf(mx, __shfl_xor(mx, 8));
            const float mt = fmaxf(m_r[r], mx);
            const float al = __expf(m_r[r] - mt);
            float sum = 0.f;
#pragma unroll
            for (int jn = 0; jn < 4; ++jn) {
                float p = __expf(S[jn][r] - mt);
                S[jn][r] = p;
                sum += p;
            }
            sum += __shfl_xor(sum, 1);
            sum += __shfl_xor(sum, 2);
            sum += __shfl_xor(sum, 4);
            sum += __shfl_xor(sum, 8);
            m_r[r] = mt;
            l_r[r] = l_r[r] * al + sum;
            alpha[r] = al;
        }
        // ---- P -> LDS (wave-private rows; no barrier) + O rescale ----
#pragma unroll
        for (int jn = 0; jn < 4; ++jn)
#pragma unroll
            for (int r = 0; r < 4; ++r)
                Ps[(wave * 16 + quad * 4 + r) * QROW + jn * 16 + c16] = __float2bfloat16(S[jn][r]);
#pragma unroll
        for (int jd = 0; jd < 4; ++jd)
#pragma unroll
            for (int r = 0; r < 4; ++r) O[jd][r] *= alpha[r];
        // ---- PV: A from Ps, B direct from transposed V in global ----
        bf16x8_t ap0 = *(const bf16x8_t*)(Ps + (wave * 16 + c16) * QROW + quad * 8);
        bf16x8_t ap1 = *(const bf16x8_t*)(Ps + (wave * 16 + c16) * QROW + 32 + quad * 8);
        int kc0 = k0 + quad * 8;      if (kc0 > LK - 8) kc0 = LK - 8;
        int kc1 = k0 + 32 + quad * 8; if (kc1 > LK - 8) kc1 = LK - 8;
#pragma unroll
        for (int jd = 0; jd < 4; ++jd) {
            const __hip_bfloat16* vr = vrow + (size_t)(jd * 16 + c16) * LK;
            bf16x8_t bv0 = *(const bf16x8_t*)(vr + kc0);
            bf16x8_t bv1 = *(const bf16x8_t*)(vr + kc1);
            O[jd] = __builtin_amdgcn_mfma_f32_16x16x32_bf16(ap0, bv0, O[jd], 0, 0, 0);
            O[jd] = __builtin_amdgcn_mfma_f32_16x16x32_bf16(ap1, bv1, O[jd], 0, 0, 0);
        }
    }

    // Epilogue: unnormalized partial O + (m,l)
#pragma unroll
    for (int r = 0; r < 4; ++r) {
        const int ql = wave * 16 + quad * 4 + r;
        const size_t grow = (size_t)(b * LQ + q0 + ql);
#pragma unroll
        for (int jd = 0; jd < 4; ++jd)
            Op[grow * DM + h * DK + jd * 16 + c16] = __float2bfloat16(O[jd][r]);
        if (c16 == 0) {
            size_t mli = ((size_t)b * NHEAD + h) * LQ + q0 + ql;
            mp[mli] = m_r[r];
            lp[mli] = l_r[r];
        }
    }
}

// Merge the two K-splits into ctx (in-place over p0) and zero aof.
__global__ __launch_bounds__(256)
void attn_merge_kernel(const __hip_bfloat16* __restrict__ p0,
                       const __hip_bfloat16* __restrict__ p1,
                       const float* __restrict__ mlbase,
                       __hip_bfloat16* __restrict__ ctx,
                       float* __restrict__ aof)
{
    const int row = blockIdx.x;            // (b,q) flat
    const int b = row / LQ, q = row - b * LQ;
    const int tid = threadIdx.x;
#pragma unroll
    for (int i = 0; i < 3; ++i) {
        const int c = tid + i * 256;
        const int h = c >> 6;
        const size_t mli = ((size_t)b * NHEAD + h) * LQ + q;
        const float m0 = mlbase[mli],              l0 = mlbase[ML_CNT + mli];
        const float m1 = mlbase[2 * ML_CNT + mli], l1 = mlbase[3 * ML_CNT + mli];
        const float mm = fmaxf(m0, m1);
        const float w0 = __expf(m0 - mm), w1 = __expf(m1 - mm);
        const float denom = l0 * w0 + l1 * w1;
        const size_t idx = (size_t)row * DM + c;
        const float v = (b2f(p0[idx]) * w0 + b2f(p1[idx]) * w1) / denom;
        ctx[idx] = __float2bfloat16(v);
        aof[idx] = 0.f;
    }
}

// ---------------------------------------------------------------------------
// LayerNorm over 768 with folded bias: x = A + F32acc + bias2.
//  MODE 0: A = flagged Xin -> bf16 ws out; also zeroes zbuf (next accumulator).
//  MODE 1: A = bf16 Xb     -> flagged-dtype d_out.
// ---------------------------------------------------------------------------
template<int MODE>
__global__ __launch_bounds__(256)
void ln_kernel(const void* __restrict__ Xin,
               const __hip_bfloat16* __restrict__ Xb,
               const float* __restrict__ Xf2f,
               const void* __restrict__ bias2,
               const void* __restrict__ g,
               const void* __restrict__ be,
               __hip_bfloat16* __restrict__ outb,
               void* __restrict__ outv,
               float* __restrict__ zbuf,
               const int* __restrict__ flagp)
{
    __shared__ float red1[256], red2[256];
    const int f32 = *flagp;
    const int row = blockIdx.x;
    const int tid = threadIdx.x;

    float x[3];
#pragma unroll
    for (int i = 0; i < 3; ++i) {
        int c = tid + i * 256;
        size_t idx = (size_t)row * DM + c;
        float a  = (MODE == 0) ? ldf(Xin, idx, f32) : b2f(Xb[idx]);
        x[i] = a + Xf2f[idx] + ldf(bias2, c, f32);
    }
    float s1 = x[0] + x[1] + x[2];
    float s2 = x[0] * x[0] + x[1] * x[1] + x[2] * x[2];
    red1[tid] = s1;
    red2[tid] = s2;
    __syncthreads();
    for (int off = 128; off > 0; off >>= 1) {
        if (tid < off) {
            red1[tid] += red1[tid + off];
            red2[tid] += red2[tid + off];
        }
        __syncthreads();
    }
    float mu   = red1[0] * (1.f / DM);
    float var  = red2[0] * (1.f / DM) - mu * mu;
    float rstd = rsqrtf(var + 1e-5f);
#pragma unroll
    for (int i = 0; i < 3; ++i) {
        int c = tid + i * 256;
        size_t idx = (size_t)row * DM + c;
        float v = (x[i] - mu) * rstd * ldf(g, c, f32) + ldf(be, c, f32);
        if (MODE == 0) {
            outb[idx] = __float2bfloat16(v);
            zbuf[idx] = 0.f;
        } else {
            if (f32) ((float*)outv)[idx] = v;
            else     ((__hip_bfloat16*)outv)[idx] = __float2bfloat16(v);
        }
    }
}

// ---------------------------------------------------------------------------
extern "C" void kernel_launch(void* const* d_in, const int* in_sizes, int n_in,
                              void* d_out, int out_size, void* d_ws, size_t ws_size,
                              hipStream_t stream)
{
    const void* docqa = d_in[0];
    const void* im    = d_in[1];
    const int* dqx = (const int*)d_in[2];
    const int* dqy = (const int*)d_in[3];
    const int* imx = (const int*)d_in[4];
    const int* imy = (const int*)d_in[5];
    const void* Wq = d_in[6];
    const void* bq = d_in[7];
    const void* Wk = d_in[8];
    const void* bk = d_in[9];
    const void* Wv = d_in[10];
    const void* bv = d_in[11];
    const void* Wo = d_in[12];
    const void* bo = d_in[13];
    const void* bias_x = d_in[14];
    const void* bias_y = d_in[15];
    const void* W1 = d_in[16];
    const void* b1 = d_in[17];
    const void* W2 = d_in[18];
    const void* b2 = d_in[19];
    const void* g1  = d_in[20];
    const void* be1 = d_in[21];
    const void* g2  = d_in[22];
    const void* be2 = d_in[23];

    // Workspace pool: 39.6 MB, proven since round 3 (DO NOT GROW).
    //   flag @0; R1 3.93M; R2 11.89M; R3 11.89M; R4 11.89M   [bytes]
    // R1 (qR): Wt3 (3.54M, dead after qkv) -> WtO (1.18M, dead after skWo)
    //          -> first part of mid
    // R2 (kb): k row-major -> rest of mid (R1+R2 contiguous, 15.73<=15.82)
    // R3 (vtb): V^T -> aof f32 (7.86M) -> W1t[0,4.72M)+W2t[4.72,9.44M)
    // R4 (cb): fullA bf16 (11.89M, dead after qkv)
    //          -> p0[0,3.93M) -> ctx -> src1; p1[3.93,7.86M); ml[7.86,8.36M)
    //          -> fof f32 [3.93,11.79M) (zeroed in LN1 after p1/ml die)
    // q lives in d_out (bf16 3.93M <= d_out size in both dtype worlds;
    // LN2 overwrites d_out at the end).
    char* w = (char*)d_ws;
    int*            flagp = (int*)w;
    __hip_bfloat16* qR  = (__hip_bfloat16*)(w + 256);
    __hip_bfloat16* kb  = qR + (size_t)M_DOC  * DM;
    __hip_bfloat16* vtb = kb + (size_t)M_FULL * DM;
    __hip_bfloat16* cb  = vtb + (size_t)M_FULL * DM;
    char* cbB = (char*)cb;

    __hip_bfloat16* fullA = cb;
    __hip_bfloat16* Wt3  = qR;
    __hip_bfloat16* WtO  = qR;
    __hip_bfloat16* qout = (__hip_bfloat16*)d_out;
    __hip_bfloat16* p0   = cb;
    __hip_bfloat16* p1   = (__hip_bfloat16*)(cbB + 3932160);
    float*          mlb  = (float*)(cbB + 7864320);
    __hip_bfloat16* ctx  = cb;
    __hip_bfloat16* src1 = cb;
    float*          fof  = (float*)(cbB + 3932160);
    float*          aof  = (float*)vtb;
    __hip_bfloat16* W1t  = vtb;
    __hip_bfloat16* W2t  = vtb + (size_t)DFF * DM;
    __hip_bfloat16* mid  = qR;

    dim3 blk(256);

    // flag + fullA bf16 conversion (concat im||docqa)
    prep_conv_kernel<<<dim3((M_FULL * (DM / 8) + 255) / 256), blk, 0, stream>>>(
        g1, flagp, im, docqa, fullA);
    // Wq/Wk/Wv transposes -> Wt3 (in R1)
    wtrans3_kernel<<<dim3(3 * 576), blk, 0, stream>>>(Wq, Wk, Wv, Wt3, flagp);
    // fused q/k/v projection (m97 A-path from fullA; q -> d_out scratch)
    qkv_gemm<<<dim3(3 * DM / 128, (M_FULL + 127) / 128), blk, 0, stream>>>(
        fullA, Wt3, bq, bk, bv, qout, kb, vtb, flagp);
    // attention, K-split S=2, direct-global operand feed (fullA dead -> p0/p1/ml)
    attn_part_kernel<<<dim3(LQ / 64, NHEAD, B * 2), blk, 0, stream>>>(
        qout, kb, vtb, dqx, dqy, imx, imy, bias_x, bias_y, p0, p1, mlb, flagp);
    // merge partials -> ctx; zero aof (V^T dead)
    attn_merge_kernel<<<dim3(M_DOC), blk, 0, stream>>>(p0, p1, mlb, ctx, aof);
    // Wo transpose over dead Wt3
    wtransO_kernel<<<dim3(576), blk, 0, stream>>>(Wo, WtO, flagp);
    // attn_out: split-K S=4 atomics into aof. bo folded into LN1.
    sk_gemm<<<dim3(DM / 128, M_DOC / 128, 4), blk, 0, stream>>>(
        ctx, WtO, aof, M_DOC, DM, DM, 4);
    // src1 = LN(docqa + aof + bo); also zero fof
    ln_kernel<0><<<dim3(M_DOC), blk, 0, stream>>>(
        docqa, nullptr, aof, bo, g1, be1, src1, nullptr, fof, flagp);
    // FFN weight transposes (over dead aof region)
    wtransW_kernel<<<dim3(2 * 2304), blk, 0, stream>>>(W1, W2, W1t, W2t, flagp);
    // mid = relu(src1 @ W1 + b1) -> R1+R2 (WtO dead)
    mfma_gemm_relu<<<dim3(DFF / 128, M_DOC / 128), blk, 0, stream>>>(
        src1, W1t, b1, mid, flagp, M_DOC, DFF, DM);
    // ffn: split-K S=4 atomics into fof. b2 folded into LN2.
    sk_gemm<<<dim3(DM / 128, M_DOC / 128, 4), blk, 0, stream>>>(
        mid, W2t, fof, M_DOC, DM, DFF, 4);
    // out = LN(src1 + fof + b2) -> d_out (overwrites q scratch)
    ln_kernel<1><<<dim3(M_DOC), blk, 0, stream>>>(
        nullptr, src1, fof, b2, g2, be2, nullptr, d_out, nullptr, flagp);
}

// Round 10
// 421.743 us; speedup vs baseline: 1.1475x; 1.1475x over previous
//
#include <hip/hip_runtime.h>
#include <hip/hip_bf16.h>

// Problem constants
constexpr int B      = 4;
constexpr int LQ     = 640;
constexpr int LIM    = 1296;
constexpr int LK     = LQ + LIM;   // 1936
constexpr int DM     = 768;
constexpr int NHEAD  = 12;
constexpr int DK     = 64;
constexpr int DFF    = 3072;
constexpr int MAXD   = 100;
constexpr int M_DOC  = B * LQ;     // 2560
constexpr int M_FULL = B * LK;     // 7744
constexpr size_t ML_CNT = (size_t)B * NHEAD * LQ;   // 30720 (m,l) rows per split

typedef __attribute__((ext_vector_type(8))) short bf16x8_t;   // 8 bf16 = 4 VGPRs
typedef __attribute__((ext_vector_type(4))) float f32x4_t;    // MFMA C/D

__device__ __forceinline__ float b2f(__hip_bfloat16 x) { return __bfloat162float(x); }

__device__ __forceinline__ float ldf(const void* p, size_t i, int f32flag) {
    return f32flag ? ((const float*)p)[i]
                   : b2f(((const __hip_bfloat16*)p)[i]);
}

// async global->LDS, 16 bytes per lane. LDS dest = wave-uniform base + lane*16.
__device__ __forceinline__ void gl_lds16(const void* g, void* l) {
    __builtin_amdgcn_global_load_lds(
        (const __attribute__((address_space(1))) unsigned int*)g,
        (__attribute__((address_space(3))) unsigned int*)l, 16, 0, 0);
}

// ---------------------------------------------------------------------------
// prep: dtype flag + concat(im,docqa) -> contiguous bf16 fullA + fused
// branch-free coordinate arrays cx/cy[b][LK] (round-9 lesson: divergent-base
// gathers in the attention K-loop defeat compiler latency hiding).
// ---------------------------------------------------------------------------
__global__ __launch_bounds__(256)
void prep_conv_kernel(const void* __restrict__ g1, int* __restrict__ flagp,
                      const void* __restrict__ im, const void* __restrict__ docqa,
                      const int* __restrict__ dqx, const int* __restrict__ dqy,
                      const int* __restrict__ imx, const int* __restrict__ imy,
                      __hip_bfloat16* __restrict__ fullA,
                      int* __restrict__ cx, int* __restrict__ cy)
{
    const bool f32 = ((*(const unsigned*)g1) & 0xFFFFu) == 0u;
    if (blockIdx.x == 0 && threadIdx.x == 0) *flagp = f32 ? 1 : 0;

    const int gid = blockIdx.x * 256 + threadIdx.x;
    if (gid < B * LK) {
        int b = gid / LK, l = gid - b * LK;
        cx[gid] = (l < LIM) ? imx[b * LIM + l] : dqx[b * LQ + l - LIM];
        cy[gid] = (l < LIM) ? imy[b * LIM + l] : dqy[b * LQ + l - LIM];
    }

    if (gid >= M_FULL * (DM / 8)) return;
    const int row = gid / (DM / 8);
    const int col = (gid - row * (DM / 8)) * 8;
    const int b   = row / LK;
    const int l   = row - b * LK;
    const size_t srow = (l < LIM) ? ((size_t)(b * LIM + l)) * DM
                                  : ((size_t)(b * LQ + (l - LIM))) * DM;
    const void* src = (l < LIM) ? im : docqa;
    union { bf16x8_t v; __hip_bfloat16 h[8]; } pk;
    if (f32) {
        const float4* fp = (const float4*)((const float*)src + srow + col);
        float4 a = fp[0], c = fp[1];
        pk.h[0] = __float2bfloat16(a.x); pk.h[1] = __float2bfloat16(a.y);
        pk.h[2] = __float2bfloat16(a.z); pk.h[3] = __float2bfloat16(a.w);
        pk.h[4] = __float2bfloat16(c.x); pk.h[5] = __float2bfloat16(c.y);
        pk.h[6] = __float2bfloat16(c.z); pk.h[7] = __float2bfloat16(c.w);
    } else {
        pk.v = *(const bf16x8_t*)((const __hip_bfloat16*)src + srow + col);
    }
    *(bf16x8_t*)(fullA + (size_t)row * DM + col) = pk.v;
}

// ---------------------------------------------------------------------------
// Transpose 32x32 tile helper (K x N flagged -> N x K bf16).
// ---------------------------------------------------------------------------
__device__ __forceinline__ void wtrans_tile(const void* W, __hip_bfloat16* Wt,
                                            int f32, int K, int N, int n0, int k0,
                                            __hip_bfloat16 (*t)[33])
{
    const int tx = threadIdx.x & 31, ty = threadIdx.x >> 5;
#pragma unroll
    for (int j = 0; j < 4; ++j) {
        int k = ty + j * 8;
        t[k][tx] = __float2bfloat16(ldf(W, (size_t)(k0 + k) * N + n0 + tx, f32));
    }
    __syncthreads();
#pragma unroll
    for (int j = 0; j < 4; ++j) {
        int n = ty + j * 8;
        Wt[(size_t)(n0 + n) * K + k0 + tx] = t[tx][n];
    }
}

// Wq,Wk,Wv -> Wt3 (2304 x 768). 3*576 blocks.
__global__ __launch_bounds__(256)
void wtrans3_kernel(const void* __restrict__ Wq, const void* __restrict__ Wk,
                    const void* __restrict__ Wv, __hip_bfloat16* __restrict__ Wt3,
                    const int* __restrict__ flagp)
{
    __shared__ __hip_bfloat16 t[32][33];
    const int f32 = *flagp;
    const int wid = blockIdx.x / 576;
    const int tt  = blockIdx.x % 576;
    const void* W = (wid == 0) ? Wq : (wid == 1) ? Wk : Wv;
    wtrans_tile(W, Wt3 + (size_t)wid * DM * DM, f32, DM, DM,
                (tt % 24) * 32, (tt / 24) * 32, t);
}

// Wo -> WtO. 576 blocks.
__global__ __launch_bounds__(256)
void wtransO_kernel(const void* __restrict__ Wo, __hip_bfloat16* __restrict__ WtO,
                    const int* __restrict__ flagp)
{
    __shared__ __hip_bfloat16 t[32][33];
    const int f32 = *flagp;
    const int tt  = blockIdx.x;
    wtrans_tile(Wo, WtO, f32, DM, DM, (tt % 24) * 32, (tt / 24) * 32, t);
}

// W1 (768x3072) -> W1t, W2 (3072x768) -> W2t. 2*2304 blocks.
__global__ __launch_bounds__(256)
void wtransW_kernel(const void* __restrict__ W1, const void* __restrict__ W2,
                    __hip_bfloat16* __restrict__ W1t, __hip_bfloat16* __restrict__ W2t,
                    const int* __restrict__ flagp)
{
    __shared__ __hip_bfloat16 t[32][33];
    const int f32 = *flagp;
    int bx = blockIdx.x;
    const bool second = bx >= 2304;
    const void* W = second ? W2 : W1;
    __hip_bfloat16* dst = second ? W2t : W1t;
    const int K = second ? DFF : DM;
    const int N = second ? DM : DFF;
    const int tt = second ? bx - 2304 : bx;
    const int nt = N / 32;
    wtrans_tile(W, dst, f32, K, N, (tt % nt) * 32, (tt / nt) * 32, t);
}

// ---------------------------------------------------------------------------
// Fused QKV GEMM, pure m97 structure: A = fullA bf16 via global_load_lds.
// q (doc rows, *1/8) -> qout (d_out scratch); k row-major; V transposed
// per (b,h): vtb[((b*NHEAD+h)*DK + d) * LK + kk].
// ---------------------------------------------------------------------------
__global__ __launch_bounds__(256)
void qkv_gemm(const __hip_bfloat16* __restrict__ fullA,
              const __hip_bfloat16* __restrict__ Wt3,
              const void* __restrict__ bq,
              const void* __restrict__ bk,
              const void* __restrict__ bv,
              __hip_bfloat16* __restrict__ qout,
              __hip_bfloat16* __restrict__ kb,
              __hip_bfloat16* __restrict__ vtb,
              const int* __restrict__ flagp)
{
    __shared__ __hip_bfloat16 Als[128 * 32];
    __shared__ __hip_bfloat16 Bls[128 * 32];

    const int f32  = *flagp;
    const int tid  = threadIdx.x;
    const int lane = tid & 63;
    const int wave = tid >> 6;
    const int quad = lane >> 4;
    const int c16  = lane & 15;
    const int n0   = blockIdx.x * 128;
    const int m0   = blockIdx.y * 128;
    const int wm   = (wave >> 1) * 64;
    const int wn   = (wave & 1) * 64;
    constexpr int K = DM;

    f32x4_t acc[4][4] = {};

    for (int k0 = 0; k0 < K; k0 += 32) {
#pragma unroll
        for (int p = 0; p < 2; ++p) {
            const int lin = p * 64 + lane;
            int row = wave * 32 + (lin >> 2);
            int gr  = m0 + row; if (gr > M_FULL - 1) gr = M_FULL - 1;
            gl_lds16(fullA + (size_t)gr * K + k0 + (lin & 3) * 8,
                     Als + wave * 1024 + p * 512);
        }
#pragma unroll
        for (int p = 0; p < 2; ++p) {
            const int lin = p * 64 + lane;
            const int row = wave * 32 + (lin >> 2);
            gl_lds16(Wt3 + (size_t)(n0 + row) * K + k0 + (lin & 3) * 8,
                     Bls + wave * 1024 + p * 512);
        }
        __syncthreads();

        bf16x8_t af[4], bfr[4];
#pragma unroll
        for (int i = 0; i < 4; ++i)
            af[i] = *(const bf16x8_t*)(Als + (wm + i * 16 + c16) * 32 + quad * 8);
#pragma unroll
        for (int j = 0; j < 4; ++j)
            bfr[j] = *(const bf16x8_t*)(Bls + (wn + j * 16 + c16) * 32 + quad * 8);
#pragma unroll
        for (int i = 0; i < 4; ++i)
#pragma unroll
            for (int j = 0; j < 4; ++j)
                acc[i][j] = __builtin_amdgcn_mfma_f32_16x16x32_bf16(af[i], bfr[j], acc[i][j], 0, 0, 0);
        __syncthreads();
    }

    const int seg = n0 / DM;                 // 0=q 1=k 2=v
    const void* bptr = (seg == 0) ? bq : (seg == 1) ? bk : bv;
#pragma unroll
    for (int j = 0; j < 4; ++j) {
        const int col  = n0 + wn + j * 16 + c16;
        const int ncol = col - seg * DM;
        const float bj = ldf(bptr, ncol, f32);
        if (seg == 2) {
            // V transposed: vtb[((bb*NHEAD+h)*DK+d)*LK + kk]
            const int h = ncol >> 6, d = ncol & 63;
#pragma unroll
            for (int i = 0; i < 4; ++i) {
                const int rowb = m0 + wm + i * 16 + quad * 4;
                const int bb0  = rowb / LK;
                const int l0   = rowb - bb0 * LK;
                if (l0 + 3 < LK && rowb + 3 < M_FULL) {
                    union { ushort4 u4; __hip_bfloat16 hh[4]; } pk;
#pragma unroll
                    for (int r = 0; r < 4; ++r)
                        pk.hh[r] = __float2bfloat16(acc[i][j][r] + bj);
                    *(ushort4*)(vtb + ((size_t)((bb0 * NHEAD + h) * DK + d)) * LK + l0) = pk.u4;
                } else {
#pragma unroll
                    for (int r = 0; r < 4; ++r) {
                        const int row = rowb + r;
                        if (row < M_FULL) {
                            int bb = row / LK, l = row - bb * LK;
                            vtb[((size_t)((bb * NHEAD + h) * DK + d)) * LK + l] =
                                __float2bfloat16(acc[i][j][r] + bj);
                        }
                    }
                }
            }
        } else {
            const float scl = (seg == 0) ? 0.125f : 1.f;
#pragma unroll
            for (int i = 0; i < 4; ++i) {
                const int rowb = m0 + wm + i * 16 + quad * 4;
#pragma unroll
                for (int r = 0; r < 4; ++r) {
                    const int row = rowb + r;
                    if (row < M_FULL) {
                        __hip_bfloat16 hv = __float2bfloat16((acc[i][j][r] + bj) * scl);
                        if (seg == 1) kb[(size_t)row * DM + ncol] = hv;
                        else {
                            int bb = row / LK, l = row - bb * LK;
                            if (l >= LIM)
                                qout[(size_t)(bb * LQ + (l - LIM)) * DM + ncol] = hv;
                        }
                    }
                }
            }
        }
    }
}

// Standard MFMA GEMM (bias + relu) for FFN1.
__global__ __launch_bounds__(256)
void mfma_gemm_relu(const __hip_bfloat16* __restrict__ Abf,
                    const __hip_bfloat16* __restrict__ Wt,
                    const void* __restrict__ bias,
                    __hip_bfloat16* __restrict__ Cc,
                    const int* __restrict__ flagp,
                    int M, int N, int K)
{
    __shared__ __hip_bfloat16 Als[128 * 32];
    __shared__ __hip_bfloat16 Bls[128 * 32];

    const int f32  = *flagp;
    const int tid  = threadIdx.x;
    const int lane = tid & 63;
    const int wave = tid >> 6;
    const int quad = lane >> 4;
    const int c16  = lane & 15;
    const int n0   = blockIdx.x * 128;
    const int m0   = blockIdx.y * 128;
    const int wm   = (wave >> 1) * 64;
    const int wn   = (wave & 1) * 64;

    f32x4_t acc[4][4] = {};

    for (int k0 = 0; k0 < K; k0 += 32) {
#pragma unroll
        for (int p = 0; p < 2; ++p) {
            const int lin = p * 64 + lane;
            int row = wave * 32 + (lin >> 2);
            int gr  = m0 + row; if (gr > M - 1) gr = M - 1;
            gl_lds16(Abf + (size_t)gr * K + k0 + (lin & 3) * 8, Als + wave * 1024 + p * 512);
        }
#pragma unroll
        for (int p = 0; p < 2; ++p) {
            const int lin = p * 64 + lane;
            const int row = wave * 32 + (lin >> 2);
            gl_lds16(Wt + (size_t)(n0 + row) * K + k0 + (lin & 3) * 8,
                     Bls + wave * 1024 + p * 512);
        }
        __syncthreads();

        bf16x8_t af[4], bfr[4];
#pragma unroll
        for (int i = 0; i < 4; ++i)
            af[i] = *(const bf16x8_t*)(Als + (wm + i * 16 + c16) * 32 + quad * 8);
#pragma unroll
        for (int j = 0; j < 4; ++j)
            bfr[j] = *(const bf16x8_t*)(Bls + (wn + j * 16 + c16) * 32 + quad * 8);
#pragma unroll
        for (int i = 0; i < 4; ++i)
#pragma unroll
            for (int j = 0; j < 4; ++j)
                acc[i][j] = __builtin_amdgcn_mfma_f32_16x16x32_bf16(af[i], bfr[j], acc[i][j], 0, 0, 0);
        __syncthreads();
    }

#pragma unroll
    for (int j = 0; j < 4; ++j) {
        const int col = n0 + wn + j * 16 + c16;
        const float bj = ldf(bias, col, f32);
#pragma unroll
        for (int i = 0; i < 4; ++i) {
            const int rowb = m0 + wm + i * 16 + quad * 4;
#pragma unroll
            for (int r = 0; r < 4; ++r) {
                const int row = rowb + r;
                if (row < M) {
                    float v = fmaxf(acc[i][j][r] + bj, 0.f);
                    Cc[(size_t)row * N + col] = __float2bfloat16(v);
                }
            }
        }
    }
}

// Split-K MFMA GEMM: f32 atomic accumulate (dest pre-zeroed), grid z = chunk.
__global__ __launch_bounds__(256)
void sk_gemm(const __hip_bfloat16* __restrict__ Abf,
             const __hip_bfloat16* __restrict__ Wt,
             float* __restrict__ Cc,
             int M, int N, int K, int S)
{
    __shared__ __hip_bfloat16 Als[128 * 32];
    __shared__ __hip_bfloat16 Bls[128 * 32];

    const int tid  = threadIdx.x;
    const int lane = tid & 63;
    const int wave = tid >> 6;
    const int quad = lane >> 4;
    const int c16  = lane & 15;
    const int n0   = blockIdx.x * 128;
    const int m0   = blockIdx.y * 128;
    const int wm   = (wave >> 1) * 64;
    const int wn   = (wave & 1) * 64;
    const int kchunk = K / S;
    const int kbeg = blockIdx.z * kchunk;

    f32x4_t acc[4][4] = {};

    for (int k0 = kbeg; k0 < kbeg + kchunk; k0 += 32) {
#pragma unroll
        for (int p = 0; p < 2; ++p) {
            const int lin = p * 64 + lane;
            int row = wave * 32 + (lin >> 2);
            int gr  = m0 + row; if (gr > M - 1) gr = M - 1;
            gl_lds16(Abf + (size_t)gr * K + k0 + (lin & 3) * 8, Als + wave * 1024 + p * 512);
        }
#pragma unroll
        for (int p = 0; p < 2; ++p) {
            const int lin = p * 64 + lane;
            const int row = wave * 32 + (lin >> 2);
            gl_lds16(Wt + (size_t)(n0 + row) * K + k0 + (lin & 3) * 8,
                     Bls + wave * 1024 + p * 512);
        }
        __syncthreads();

        bf16x8_t af[4], bfr[4];
#pragma unroll
        for (int i = 0; i < 4; ++i)
            af[i] = *(const bf16x8_t*)(Als + (wm + i * 16 + c16) * 32 + quad * 8);
#pragma unroll
        for (int j = 0; j < 4; ++j)
            bfr[j] = *(const bf16x8_t*)(Bls + (wn + j * 16 + c16) * 32 + quad * 8);
#pragma unroll
        for (int i = 0; i < 4; ++i)
#pragma unroll
            for (int j = 0; j < 4; ++j)
                acc[i][j] = __builtin_amdgcn_mfma_f32_16x16x32_bf16(af[i], bfr[j], acc[i][j], 0, 0, 0);
        __syncthreads();
    }

#pragma unroll
    for (int j = 0; j < 4; ++j) {
        const int col = n0 + wn + j * 16 + c16;
#pragma unroll
        for (int i = 0; i < 4; ++i) {
            const int rowb = m0 + wm + i * 16 + quad * 4;
#pragma unroll
            for (int r = 0; r < 4; ++r) {
                const int row = rowb + r;
                if (row < M) atomicAdd(&Cc[(size_t)row * N + col], acc[i][j][r]);
            }
        }
    }
}

// ---------------------------------------------------------------------------
// MFMA flash attention, direct-global operand feed, K-split S=2.
// Grid (10, 12, B*2): b=z&3, s=z>>2. Branch-free fused coords cx/cy (single
// base — keeps the gathers hoistable/pipelinable by the compiler).
// Writes unnormalized partial O (bf16) + per-(b,h,q) m,l.
// ---------------------------------------------------------------------------
__global__ __launch_bounds__(256)
void attn_part_kernel(const __hip_bfloat16* __restrict__ Qb,
                      const __hip_bfloat16* __restrict__ Kb,
                      const __hip_bfloat16* __restrict__ Vtb,
                      const int* __restrict__ cx, const int* __restrict__ cy,
                      const void* __restrict__ bias_x,
                      const void* __restrict__ bias_y,
                      __hip_bfloat16* __restrict__ p0,
                      __hip_bfloat16* __restrict__ p1,
                      float* __restrict__ mlbase,
                      const int* __restrict__ flagp)
{
    constexpr int QT = 64, KT = 64;
    constexpr int QROW = 72;
    __shared__ __hip_bfloat16 Ps[QT * QROW];
    __shared__ float bxs[2 * MAXD + 1], bys[2 * MAXD + 1];

    const int f32  = *flagp;
    const int tid  = threadIdx.x;
    const int lane = tid & 63;
    const int wave = tid >> 6;
    const int quad = lane >> 4;
    const int c16  = lane & 15;
    const int h    = blockIdx.y;
    const int b    = blockIdx.z & 3;
    const int s    = blockIdx.z >> 2;
    const int q0   = blockIdx.x * QT;
    const int kbeg = s * 1024;
    const int kend = s ? LK : 1024;

    __hip_bfloat16* Op = s ? p1 : p0;
    float* mp = mlbase + (size_t)s * 2 * ML_CNT;
    float* lp = mp + ML_CNT;

    for (int i = tid; i < 2 * MAXD + 1; i += 256) {
        bxs[i] = ldf(bias_x, (size_t)i * NHEAD + h, f32);
        bys[i] = ldf(bias_y, (size_t)i * NHEAD + h, f32);
    }

    // Loop-invariant Q fragments + q coords (direct global, single base)
    const __hip_bfloat16* qrow = Qb + ((size_t)(b * LQ + q0 + wave * 16 + c16)) * DM + h * DK;
    const bf16x8_t aq0 = *(const bf16x8_t*)(qrow + quad * 8);
    const bf16x8_t aq1 = *(const bf16x8_t*)(qrow + 32 + quad * 8);
    int qx[4], qy[4];
#pragma unroll
    for (int r = 0; r < 4; ++r) {
        const int qi = b * LK + LIM + q0 + wave * 16 + quad * 4 + r;
        qx[r] = cx[qi]; qy[r] = cy[qi];
    }
    const __hip_bfloat16* vrow = Vtb + ((size_t)((b * NHEAD + h) * DK)) * LK;

    __syncthreads();   // bias tables visible

    f32x4_t O[4] = {};
    float m_r[4], l_r[4];
#pragma unroll
    for (int r = 0; r < 4; ++r) { m_r[r] = -1e30f; l_r[r] = 0.f; }

    for (int k0 = kbeg; k0 < kend; k0 += KT) {
        // ---- scores: direct-global K fragments ----
        f32x4_t S[4];
#pragma unroll
        for (int jn = 0; jn < 4; ++jn) {
            int krow = k0 + jn * 16 + c16; if (krow > LK - 1) krow = LK - 1;
            const __hip_bfloat16* kr = Kb + ((size_t)(b * LK + krow)) * DM + h * DK;
            bf16x8_t bk0 = *(const bf16x8_t*)(kr + quad * 8);
            bf16x8_t bk1 = *(const bf16x8_t*)(kr + 32 + quad * 8);
            f32x4_t acc = {0.f, 0.f, 0.f, 0.f};
            acc = __builtin_amdgcn_mfma_f32_16x16x32_bf16(aq0, bk0, acc, 0, 0, 0);
            acc = __builtin_amdgcn_mfma_f32_16x16x32_bf16(aq1, bk1, acc, 0, 0, 0);
            S[jn] = acc;
        }
        // ---- bias + tail mask (branch-free single-base coord gather) ----
#pragma unroll
        for (int jn = 0; jn < 4; ++jn) {
            const int kg = k0 + jn * 16 + c16;
            const bool ok = kg < LK;
            const int kgc = ok ? kg : LK - 1;
            const int kx = cx[b * LK + kgc], ky = cy[b * LK + kgc];
#pragma unroll
            for (int r = 0; r < 4; ++r) {
                int rx = min(max(qx[r] - kx, -MAXD), MAXD) + MAXD;
                int ry = min(max(qy[r] - ky, -MAXD), MAXD) + MAXD;
                float v = S[jn][r] + bxs[rx] + bys[ry];
                S[jn][r] = ok ? v : -1e30f;
            }
        }
        // ---- online softmax (registers + shfl over 16-lane row group) ----
        float alpha[4];
#pragma unroll
        for (int r = 0; r < 4; ++r) {
            float mx = fmaxf(fmaxf(S[0][r], S[1][r]), fmaxf(S[2][r], S[3][r]));
            mx = fmaxf(mx, __shfl_xor(mx, 1));
            mx = fmaxf(mx, __shfl_xor(mx, 2));
            mx = fmaxf(mx, __shfl_xor(mx, 4));
            mx = fmaxf(mx, __shfl_xor(mx, 8));
            const float mt = fmaxf(m_r[r], mx);
            const float al = __expf(m_r[r] - mt);
            float sum = 0.f;
#pragma unroll
            for (int jn = 0; jn < 4; ++jn) {
                float p = __expf(S[jn][r] - mt);
                S[jn][r] = p;
                sum += p;
            }
            sum += __shfl_xor(sum, 1);
            sum += __shfl_xor(sum, 2);
            sum += __shfl_xor(sum, 4);
            sum += __shfl_xor(sum, 8);
            m_r[r] = mt;
            l_r[r] = l_r[r] * al + sum;
            alpha[r] = al;
        }
        // ---- P -> LDS (wave-private rows; no barrier) + O rescale ----
#pragma unroll
        for (int jn = 0; jn < 4; ++jn)
#pragma unroll
            for (int r = 0; r < 4; ++r)
                Ps[(wave * 16 + quad * 4 + r) * QROW + jn * 16 + c16] = __float2bfloat16(S[jn][r]);
#pragma unroll
        for (int jd = 0; jd < 4; ++jd)
#pragma unroll
            for (int r = 0; r < 4; ++r) O[jd][r] *= alpha[r];
        // ---- PV: A from Ps, B direct from transposed V in global ----
        bf16x8_t ap0 = *(const bf16x8_t*)(Ps + (wave * 16 + c16) * QROW + quad * 8);
        bf16x8_t ap1 = *(const bf16x8_t*)(Ps + (wave * 16 + c16) * QROW + 32 + quad * 8);
        int kc0 = k0 + quad * 8;      if (kc0 > LK - 8) kc0 = LK - 8;
        int kc1 = k0 + 32 + quad * 8; if (kc1 > LK - 8) kc1 = LK - 8;
#pragma unroll
        for (int jd = 0; jd < 4; ++jd) {
            const __hip_bfloat16* vr = vrow + (size_t)(jd * 16 + c16) * LK;
            bf16x8_t bv0 = *(const bf16x8_t*)(vr + kc0);
            bf16x8_t bv1 = *(const bf16x8_t*)(vr + kc1);
            O[jd] = __builtin_amdgcn_mfma_f32_16x16x32_bf16(ap0, bv0, O[jd], 0, 0, 0);
            O[jd] = __builtin_amdgcn_mfma_f32_16x16x32_bf16(ap1, bv1, O[jd], 0, 0, 0);
        }
    }

    // Epilogue: unnormalized partial O + (m,l)
#pragma unroll
    for (int r = 0; r < 4; ++r) {
        const int ql = wave * 16 + quad * 4 + r;
        const size_t grow = (size_t)(b * LQ + q0 + ql);
#pragma unroll
        for (int jd = 0; jd < 4; ++jd)
            Op[grow * DM + h * DK + jd * 16 + c16] = __float2bfloat16(O[jd][r]);
        if (c16 == 0) {
            size_t mli = ((size_t)b * NHEAD + h) * LQ + q0 + ql;
            mp[mli] = m_r[r];
            lp[mli] = l_r[r];
        }
    }
}

// Merge the two K-splits into ctx (in-place over p0) and zero aof.
__global__ __launch_bounds__(256)
void attn_merge_kernel(const __hip_bfloat16* __restrict__ p0,
                       const __hip_bfloat16* __restrict__ p1,
                       const float* __restrict__ mlbase,
                       __hip_bfloat16* __restrict__ ctx,
                       float* __restrict__ aof)
{
    const int row = blockIdx.x;            // (b,q) flat
    const int b = row / LQ, q = row - b * LQ;
    const int tid = threadIdx.x;
#pragma unroll
    for (int i = 0; i < 3; ++i) {
        const int c = tid + i * 256;
        const int h = c >> 6;
        const size_t mli = ((size_t)b * NHEAD + h) * LQ + q;
        const float m0 = mlbase[mli],              l0 = mlbase[ML_CNT + mli];
        const float m1 = mlbase[2 * ML_CNT + mli], l1 = mlbase[3 * ML_CNT + mli];
        const float mm = fmaxf(m0, m1);
        const float w0 = __expf(m0 - mm), w1 = __expf(m1 - mm);
        const float denom = l0 * w0 + l1 * w1;
        const size_t idx = (size_t)row * DM + c;
        const float v = (b2f(p0[idx]) * w0 + b2f(p1[idx]) * w1) / denom;
        ctx[idx] = __float2bfloat16(v);
        aof[idx] = 0.f;
    }
}

// ---------------------------------------------------------------------------
// LayerNorm over 768 with folded bias: x = A + F32acc + bias2.
//  MODE 0: A = flagged Xin -> bf16 ws out; also zeroes zbuf (next accumulator).
//  MODE 1: A = bf16 Xb     -> flagged-dtype d_out.
// ---------------------------------------------------------------------------
template<int MODE>
__global__ __launch_bounds__(256)
void ln_kernel(const void* __restrict__ Xin,
               const __hip_bfloat16* __restrict__ Xb,
               const float* __restrict__ Xf2f,
               const void* __restrict__ bias2,
               const void* __restrict__ g,
               const void* __restrict__ be,
               __hip_bfloat16* __restrict__ outb,
               void* __restrict__ outv,
               float* __restrict__ zbuf,
               const int* __restrict__ flagp)
{
    __shared__ float red1[256], red2[256];
    const int f32 = *flagp;
    const int row = blockIdx.x;
    const int tid = threadIdx.x;

    float x[3];
#pragma unroll
    for (int i = 0; i < 3; ++i) {
        int c = tid + i * 256;
        size_t idx = (size_t)row * DM + c;
        float a  = (MODE == 0) ? ldf(Xin, idx, f32) : b2f(Xb[idx]);
        x[i] = a + Xf2f[idx] + ldf(bias2, c, f32);
    }
    float s1 = x[0] + x[1] + x[2];
    float s2 = x[0] * x[0] + x[1] * x[1] + x[2] * x[2];
    red1[tid] = s1;
    red2[tid] = s2;
    __syncthreads();
    for (int off = 128; off > 0; off >>= 1) {
        if (tid < off) {
            red1[tid] += red1[tid + off];
            red2[tid] += red2[tid + off];
        }
        __syncthreads();
    }
    float mu   = red1[0] * (1.f / DM);
    float var  = red2[0] * (1.f / DM) - mu * mu;
    float rstd = rsqrtf(var + 1e-5f);
#pragma unroll
    for (int i = 0; i < 3; ++i) {
        int c = tid + i * 256;
        size_t idx = (size_t)row * DM + c;
        float v = (x[i] - mu) * rstd * ldf(g, c, f32) + ldf(be, c, f32);
        if (MODE == 0) {
            outb[idx] = __float2bfloat16(v);
            zbuf[idx] = 0.f;
        } else {
            if (f32) ((float*)outv)[idx] = v;
            else     ((__hip_bfloat16*)outv)[idx] = __float2bfloat16(v);
        }
    }
}

// ---------------------------------------------------------------------------
extern "C" void kernel_launch(void* const* d_in, const int* in_sizes, int n_in,
                              void* d_out, int out_size, void* d_ws, size_t ws_size,
                              hipStream_t stream)
{
    const void* docqa = d_in[0];
    const void* im    = d_in[1];
    const int* dqx = (const int*)d_in[2];
    const int* dqy = (const int*)d_in[3];
    const int* imx = (const int*)d_in[4];
    const int* imy = (const int*)d_in[5];
    const void* Wq = d_in[6];
    const void* bq = d_in[7];
    const void* Wk = d_in[8];
    const void* bk = d_in[9];
    const void* Wv = d_in[10];
    const void* bv = d_in[11];
    const void* Wo = d_in[12];
    const void* bo = d_in[13];
    const void* bias_x = d_in[14];
    const void* bias_y = d_in[15];
    const void* W1 = d_in[16];
    const void* b1 = d_in[17];
    const void* W2 = d_in[18];
    const void* b2 = d_in[19];
    const void* g1  = d_in[20];
    const void* be1 = d_in[21];
    const void* g2  = d_in[22];
    const void* be2 = d_in[23];

    // Workspace pool: 39.6 MB, proven since round 3 (DO NOT GROW).
    //   flag @0; R1 3.93M; R2 11.89M; R3 11.89M; R4 11.89M   [bytes]
    // R1: Wt3 [0,3.54M) (dead after qkv) + cx/cy [3.54M,3.60M) (dead after attn)
    //     -> WtO [0,1.18M) (dead after skWo) -> first part of mid
    // R2 (kb): k row-major -> rest of mid (R1+R2 contiguous, 15.73<=15.82)
    // R3 (vtb): V^T -> aof f32 (7.86M) -> W1t[0,4.72M)+W2t[4.72,9.44M)
    // R4 (cb): fullA bf16 (dead after qkv)
    //          -> p0[0,3.93M) -> ctx -> src1; p1[3.93,7.86M); ml[7.86,8.36M)
    //          -> fof f32 [3.93,11.79M) (zeroed in LN1 after p1/ml die)
    // q lives in d_out (LN2 overwrites d_out at the end).
    char* w = (char*)d_ws;
    int*            flagp = (int*)w;
    __hip_bfloat16* qR  = (__hip_bfloat16*)(w + 256);
    __hip_bfloat16* kb  = qR + (size_t)M_DOC  * DM;
    __hip_bfloat16* vtb = kb + (size_t)M_FULL * DM;
    __hip_bfloat16* cb  = vtb + (size_t)M_FULL * DM;
    char* cbB = (char*)cb;
    char* r1B = (char*)qR;

    __hip_bfloat16* fullA = cb;
    __hip_bfloat16* Wt3  = qR;
    int*            cxp  = (int*)(r1B + 3538944);     // R1 spare tail
    int*            cyp  = cxp + (size_t)B * LK;
    __hip_bfloat16* WtO  = qR;
    __hip_bfloat16* qout = (__hip_bfloat16*)d_out;
    __hip_bfloat16* p0   = cb;
    __hip_bfloat16* p1   = (__hip_bfloat16*)(cbB + 3932160);
    float*          mlb  = (float*)(cbB + 7864320);
    __hip_bfloat16* ctx  = cb;
    __hip_bfloat16* src1 = cb;
    float*          fof  = (float*)(cbB + 3932160);
    float*          aof  = (float*)vtb;
    __hip_bfloat16* W1t  = vtb;
    __hip_bfloat16* W2t  = vtb + (size_t)DFF * DM;
    __hip_bfloat16* mid  = qR;

    dim3 blk(256);

    // flag + fullA bf16 conversion + fused coord arrays
    prep_conv_kernel<<<dim3((M_FULL * (DM / 8) + 255) / 256), blk, 0, stream>>>(
        g1, flagp, im, docqa, dqx, dqy, imx, imy, fullA, cxp, cyp);
    // Wq/Wk/Wv transposes -> Wt3 (in R1)
    wtrans3_kernel<<<dim3(3 * 576), blk, 0, stream>>>(Wq, Wk, Wv, Wt3, flagp);
    // fused q/k/v projection (m97 A-path from fullA; q -> d_out scratch)
    qkv_gemm<<<dim3(3 * DM / 128, (M_FULL + 127) / 128), blk, 0, stream>>>(
        fullA, Wt3, bq, bk, bv, qout, kb, vtb, flagp);
    // attention, K-split S=2, direct-global operand feed (fullA dead -> p0/p1/ml)
    attn_part_kernel<<<dim3(LQ / 64, NHEAD, B * 2), blk, 0, stream>>>(
        qout, kb, vtb, cxp, cyp, bias_x, bias_y, p0, p1, mlb, flagp);
    // merge partials -> ctx; zero aof (V^T dead)
    attn_merge_kernel<<<dim3(M_DOC), blk, 0, stream>>>(p0, p1, mlb, ctx, aof);
    // Wo transpose over dead Wt3
    wtransO_kernel<<<dim3(576), blk, 0, stream>>>(Wo, WtO, flagp);
    // attn_out: split-K S=4 atomics into aof. bo folded into LN1.
    sk_gemm<<<dim3(DM / 128, M_DOC / 128, 4), blk, 0, stream>>>(
        ctx, WtO, aof, M_DOC, DM, DM, 4);
    // src1 = LN(docqa + aof + bo); also zero fof
    ln_kernel<0><<<dim3(M_DOC), blk, 0, stream>>>(
        docqa, nullptr, aof, bo, g1, be1, src1, nullptr, fof, flagp);
    // FFN weight transposes (over dead aof region)
    wtransW_kernel<<<dim3(2 * 2304), blk, 0, stream>>>(W1, W2, W1t, W2t, flagp);
    // mid = relu(src1 @ W1 + b1) -> R1+R2 (WtO/cx/cy dead)
    mfma_gemm_relu<<<dim3(DFF / 128, M_DOC / 128), blk, 0, stream>>>(
        src1, W1t, b1, mid, flagp, M_DOC, DFF, DM);
    // ffn: split-K S=4 atomics into fof. b2 folded into LN2.
    sk_gemm<<<dim3(DM / 128, M_DOC / 128, 4), blk, 0, stream>>>(
        mid, W2t, fof, M_DOC, DM, DFF, 4);
    // out = LN(src1 + fof + b2) -> d_out (overwrites q scratch)
    ln_kernel<1><<<dim3(M_DOC), blk, 0, stream>>>(
        nullptr, src1, fof, b2, g2, be2, nullptr, d_out, nullptr, flagp);
}

// Round 11
// 420.383 us; speedup vs baseline: 1.1512x; 1.0032x over previous
//
#include <hip/hip_runtime.h>
#include <hip/hip_bf16.h>

// Problem constants
constexpr int B      = 4;
constexpr int LQ     = 640;
constexpr int LIM    = 1296;
constexpr int LK     = LQ + LIM;   // 1936
constexpr int DM     = 768;
constexpr int NHEAD  = 12;
constexpr int DK     = 64;
constexpr int DFF    = 3072;
constexpr int MAXD   = 100;
constexpr int M_DOC  = B * LQ;     // 2560
constexpr int M_FULL = B * LK;     // 7744
constexpr size_t ML_CNT = (size_t)B * NHEAD * LQ;   // 30720 (m,l) rows per split

typedef __attribute__((ext_vector_type(8))) short bf16x8_t;   // 8 bf16 = 4 VGPRs
typedef __attribute__((ext_vector_type(4))) float f32x4_t;    // MFMA C/D

__device__ __forceinline__ float b2f(__hip_bfloat16 x) { return __bfloat162float(x); }

__device__ __forceinline__ float ldf(const void* p, size_t i, int f32flag) {
    return f32flag ? ((const float*)p)[i]
                   : b2f(((const __hip_bfloat16*)p)[i]);
}

// async global->LDS, 16 bytes per lane. LDS dest = wave-uniform base + lane*16.
__device__ __forceinline__ void gl_lds16(const void* g, void* l) {
    __builtin_amdgcn_global_load_lds(
        (const __attribute__((address_space(1))) unsigned int*)g,
        (__attribute__((address_space(3))) unsigned int*)l, 16, 0, 0);
}

// ---------------------------------------------------------------------------
// prep: dtype flag + concat(im,docqa) -> contiguous bf16 fullA + fused
// branch-free coordinate arrays cx/cy[b][LK] (round-9 lesson: divergent-base
// gathers in the attention K-loop defeat compiler latency hiding).
// ---------------------------------------------------------------------------
__global__ __launch_bounds__(256)
void prep_conv_kernel(const void* __restrict__ g1, int* __restrict__ flagp,
                      const void* __restrict__ im, const void* __restrict__ docqa,
                      const int* __restrict__ dqx, const int* __restrict__ dqy,
                      const int* __restrict__ imx, const int* __restrict__ imy,
                      __hip_bfloat16* __restrict__ fullA,
                      int* __restrict__ cx, int* __restrict__ cy)
{
    const bool f32 = ((*(const unsigned*)g1) & 0xFFFFu) == 0u;
    if (blockIdx.x == 0 && threadIdx.x == 0) *flagp = f32 ? 1 : 0;

    const int gid = blockIdx.x * 256 + threadIdx.x;
    if (gid < B * LK) {
        int b = gid / LK, l = gid - b * LK;
        cx[gid] = (l < LIM) ? imx[b * LIM + l] : dqx[b * LQ + l - LIM];
        cy[gid] = (l < LIM) ? imy[b * LIM + l] : dqy[b * LQ + l - LIM];
    }

    if (gid >= M_FULL * (DM / 8)) return;
    const int row = gid / (DM / 8);
    const int col = (gid - row * (DM / 8)) * 8;
    const int b   = row / LK;
    const int l   = row - b * LK;
    const size_t srow = (l < LIM) ? ((size_t)(b * LIM + l)) * DM
                                  : ((size_t)(b * LQ + (l - LIM))) * DM;
    const void* src = (l < LIM) ? im : docqa;
    union { bf16x8_t v; __hip_bfloat16 h[8]; } pk;
    if (f32) {
        const float4* fp = (const float4*)((const float*)src + srow + col);
        float4 a = fp[0], c = fp[1];
        pk.h[0] = __float2bfloat16(a.x); pk.h[1] = __float2bfloat16(a.y);
        pk.h[2] = __float2bfloat16(a.z); pk.h[3] = __float2bfloat16(a.w);
        pk.h[4] = __float2bfloat16(c.x); pk.h[5] = __float2bfloat16(c.y);
        pk.h[6] = __float2bfloat16(c.z); pk.h[7] = __float2bfloat16(c.w);
    } else {
        pk.v = *(const bf16x8_t*)((const __hip_bfloat16*)src + srow + col);
    }
    *(bf16x8_t*)(fullA + (size_t)row * DM + col) = pk.v;
}

// ---------------------------------------------------------------------------
// Transpose 32x32 tile helper (K x N flagged -> N x K bf16).
// ---------------------------------------------------------------------------
__device__ __forceinline__ void wtrans_tile(const void* W, __hip_bfloat16* Wt,
                                            int f32, int K, int N, int n0, int k0,
                                            __hip_bfloat16 (*t)[33])
{
    const int tx = threadIdx.x & 31, ty = threadIdx.x >> 5;
#pragma unroll
    for (int j = 0; j < 4; ++j) {
        int k = ty + j * 8;
        t[k][tx] = __float2bfloat16(ldf(W, (size_t)(k0 + k) * N + n0 + tx, f32));
    }
    __syncthreads();
#pragma unroll
    for (int j = 0; j < 4; ++j) {
        int n = ty + j * 8;
        Wt[(size_t)(n0 + n) * K + k0 + tx] = t[tx][n];
    }
}

// Wq,Wk,Wv -> Wt3 (2304 x 768). 3*576 blocks.
__global__ __launch_bounds__(256)
void wtrans3_kernel(const void* __restrict__ Wq, const void* __restrict__ Wk,
                    const void* __restrict__ Wv, __hip_bfloat16* __restrict__ Wt3,
                    const int* __restrict__ flagp)
{
    __shared__ __hip_bfloat16 t[32][33];
    const int f32 = *flagp;
    const int wid = blockIdx.x / 576;
    const int tt  = blockIdx.x % 576;
    const void* W = (wid == 0) ? Wq : (wid == 1) ? Wk : Wv;
    wtrans_tile(W, Wt3 + (size_t)wid * DM * DM, f32, DM, DM,
                (tt % 24) * 32, (tt / 24) * 32, t);
}

// Wo -> WtO. 576 blocks.
__global__ __launch_bounds__(256)
void wtransO_kernel(const void* __restrict__ Wo, __hip_bfloat16* __restrict__ WtO,
                    const int* __restrict__ flagp)
{
    __shared__ __hip_bfloat16 t[32][33];
    const int f32 = *flagp;
    const int tt  = blockIdx.x;
    wtrans_tile(Wo, WtO, f32, DM, DM, (tt % 24) * 32, (tt / 24) * 32, t);
}

// W1 (768x3072) -> W1t, W2 (3072x768) -> W2t. 2*2304 blocks.
__global__ __launch_bounds__(256)
void wtransW_kernel(const void* __restrict__ W1, const void* __restrict__ W2,
                    __hip_bfloat16* __restrict__ W1t, __hip_bfloat16* __restrict__ W2t,
                    const int* __restrict__ flagp)
{
    __shared__ __hip_bfloat16 t[32][33];
    const int f32 = *flagp;
    int bx = blockIdx.x;
    const bool second = bx >= 2304;
    const void* W = second ? W2 : W1;
    __hip_bfloat16* dst = second ? W2t : W1t;
    const int K = second ? DFF : DM;
    const int N = second ? DM : DFF;
    const int tt = second ? bx - 2304 : bx;
    const int nt = N / 32;
    wtrans_tile(W, dst, f32, K, N, (tt % nt) * 32, (tt / nt) * 32, t);
}

// ---------------------------------------------------------------------------
// Fused QKV GEMM, pure m97 structure: A = fullA bf16 via global_load_lds.
// q (doc rows, *1/8) -> qout (d_out scratch); k row-major; V transposed
// per (b,h): vtb[((b*NHEAD+h)*DK + d) * LK + kk].
// ---------------------------------------------------------------------------
__global__ __launch_bounds__(256)
void qkv_gemm(const __hip_bfloat16* __restrict__ fullA,
              const __hip_bfloat16* __restrict__ Wt3,
              const void* __restrict__ bq,
              const void* __restrict__ bk,
              const void* __restrict__ bv,
              __hip_bfloat16* __restrict__ qout,
              __hip_bfloat16* __restrict__ kb,
              __hip_bfloat16* __restrict__ vtb,
              const int* __restrict__ flagp)
{
    __shared__ __hip_bfloat16 Als[128 * 32];
    __shared__ __hip_bfloat16 Bls[128 * 32];

    const int f32  = *flagp;
    const int tid  = threadIdx.x;
    const int lane = tid & 63;
    const int wave = tid >> 6;
    const int quad = lane >> 4;
    const int c16  = lane & 15;
    const int n0   = blockIdx.x * 128;
    const int m0   = blockIdx.y * 128;
    const int wm   = (wave >> 1) * 64;
    const int wn   = (wave & 1) * 64;
    constexpr int K = DM;

    f32x4_t acc[4][4] = {};

    for (int k0 = 0; k0 < K; k0 += 32) {
#pragma unroll
        for (int p = 0; p < 2; ++p) {
            const int lin = p * 64 + lane;
            int row = wave * 32 + (lin >> 2);
            int gr  = m0 + row; if (gr > M_FULL - 1) gr = M_FULL - 1;
            gl_lds16(fullA + (size_t)gr * K + k0 + (lin & 3) * 8,
                     Als + wave * 1024 + p * 512);
        }
#pragma unroll
        for (int p = 0; p < 2; ++p) {
            const int lin = p * 64 + lane;
            const int row = wave * 32 + (lin >> 2);
            gl_lds16(Wt3 + (size_t)(n0 + row) * K + k0 + (lin & 3) * 8,
                     Bls + wave * 1024 + p * 512);
        }
        __syncthreads();

        bf16x8_t af[4], bfr[4];
#pragma unroll
        for (int i = 0; i < 4; ++i)
            af[i] = *(const bf16x8_t*)(Als + (wm + i * 16 + c16) * 32 + quad * 8);
#pragma unroll
        for (int j = 0; j < 4; ++j)
            bfr[j] = *(const bf16x8_t*)(Bls + (wn + j * 16 + c16) * 32 + quad * 8);
#pragma unroll
        for (int i = 0; i < 4; ++i)
#pragma unroll
            for (int j = 0; j < 4; ++j)
                acc[i][j] = __builtin_amdgcn_mfma_f32_16x16x32_bf16(af[i], bfr[j], acc[i][j], 0, 0, 0);
        __syncthreads();
    }

    const int seg = n0 / DM;                 // 0=q 1=k 2=v
    const void* bptr = (seg == 0) ? bq : (seg == 1) ? bk : bv;
#pragma unroll
    for (int j = 0; j < 4; ++j) {
        const int col  = n0 + wn + j * 16 + c16;
        const int ncol = col - seg * DM;
        const float bj = ldf(bptr, ncol, f32);
        if (seg == 2) {
            // V transposed: vtb[((bb*NHEAD+h)*DK+d)*LK + kk]
            const int h = ncol >> 6, d = ncol & 63;
#pragma unroll
            for (int i = 0; i < 4; ++i) {
                const int rowb = m0 + wm + i * 16 + quad * 4;
                const int bb0  = rowb / LK;
                const int l0   = rowb - bb0 * LK;
                if (l0 + 3 < LK && rowb + 3 < M_FULL) {
                    union { ushort4 u4; __hip_bfloat16 hh[4]; } pk;
#pragma unroll
                    for (int r = 0; r < 4; ++r)
                        pk.hh[r] = __float2bfloat16(acc[i][j][r] + bj);
                    *(ushort4*)(vtb + ((size_t)((bb0 * NHEAD + h) * DK + d)) * LK + l0) = pk.u4;
                } else {
#pragma unroll
                    for (int r = 0; r < 4; ++r) {
                        const int row = rowb + r;
                        if (row < M_FULL) {
                            int bb = row / LK, l = row - bb * LK;
                            vtb[((size_t)((bb * NHEAD + h) * DK + d)) * LK + l] =
                                __float2bfloat16(acc[i][j][r] + bj);
                        }
                    }
                }
            }
        } else {
            const float scl = (seg == 0) ? 0.125f : 1.f;
#pragma unroll
            for (int i = 0; i < 4; ++i) {
                const int rowb = m0 + wm + i * 16 + quad * 4;
#pragma unroll
                for (int r = 0; r < 4; ++r) {
                    const int row = rowb + r;
                    if (row < M_FULL) {
                        __hip_bfloat16 hv = __float2bfloat16((acc[i][j][r] + bj) * scl);
                        if (seg == 1) kb[(size_t)row * DM + ncol] = hv;
                        else {
                            int bb = row / LK, l = row - bb * LK;
                            if (l >= LIM)
                                qout[(size_t)(bb * LQ + (l - LIM)) * DM + ncol] = hv;
                        }
                    }
                }
            }
        }
    }
}

// Standard MFMA GEMM (bias + relu) for FFN1.
__global__ __launch_bounds__(256)
void mfma_gemm_relu(const __hip_bfloat16* __restrict__ Abf,
                    const __hip_bfloat16* __restrict__ Wt,
                    const void* __restrict__ bias,
                    __hip_bfloat16* __restrict__ Cc,
                    const int* __restrict__ flagp,
                    int M, int N, int K)
{
    __shared__ __hip_bfloat16 Als[128 * 32];
    __shared__ __hip_bfloat16 Bls[128 * 32];

    const int f32  = *flagp;
    const int tid  = threadIdx.x;
    const int lane = tid & 63;
    const int wave = tid >> 6;
    const int quad = lane >> 4;
    const int c16  = lane & 15;
    const int n0   = blockIdx.x * 128;
    const int m0   = blockIdx.y * 128;
    const int wm   = (wave >> 1) * 64;
    const int wn   = (wave & 1) * 64;

    f32x4_t acc[4][4] = {};

    for (int k0 = 0; k0 < K; k0 += 32) {
#pragma unroll
        for (int p = 0; p < 2; ++p) {
            const int lin = p * 64 + lane;
            int row = wave * 32 + (lin >> 2);
            int gr  = m0 + row; if (gr > M - 1) gr = M - 1;
            gl_lds16(Abf + (size_t)gr * K + k0 + (lin & 3) * 8, Als + wave * 1024 + p * 512);
        }
#pragma unroll
        for (int p = 0; p < 2; ++p) {
            const int lin = p * 64 + lane;
            const int row = wave * 32 + (lin >> 2);
            gl_lds16(Wt + (size_t)(n0 + row) * K + k0 + (lin & 3) * 8,
                     Bls + wave * 1024 + p * 512);
        }
        __syncthreads();

        bf16x8_t af[4], bfr[4];
#pragma unroll
        for (int i = 0; i < 4; ++i)
            af[i] = *(const bf16x8_t*)(Als + (wm + i * 16 + c16) * 32 + quad * 8);
#pragma unroll
        for (int j = 0; j < 4; ++j)
            bfr[j] = *(const bf16x8_t*)(Bls + (wn + j * 16 + c16) * 32 + quad * 8);
#pragma unroll
        for (int i = 0; i < 4; ++i)
#pragma unroll
            for (int j = 0; j < 4; ++j)
                acc[i][j] = __builtin_amdgcn_mfma_f32_16x16x32_bf16(af[i], bfr[j], acc[i][j], 0, 0, 0);
        __syncthreads();
    }

#pragma unroll
    for (int j = 0; j < 4; ++j) {
        const int col = n0 + wn + j * 16 + c16;
        const float bj = ldf(bias, col, f32);
#pragma unroll
        for (int i = 0; i < 4; ++i) {
            const int rowb = m0 + wm + i * 16 + quad * 4;
#pragma unroll
            for (int r = 0; r < 4; ++r) {
                const int row = rowb + r;
                if (row < M) {
                    float v = fmaxf(acc[i][j][r] + bj, 0.f);
                    Cc[(size_t)row * N + col] = __float2bfloat16(v);
                }
            }
        }
    }
}

// Split-K MFMA GEMM: f32 atomic accumulate (dest pre-zeroed), grid z = chunk.
__global__ __launch_bounds__(256)
void sk_gemm(const __hip_bfloat16* __restrict__ Abf,
             const __hip_bfloat16* __restrict__ Wt,
             float* __restrict__ Cc,
             int M, int N, int K, int S)
{
    __shared__ __hip_bfloat16 Als[128 * 32];
    __shared__ __hip_bfloat16 Bls[128 * 32];

    const int tid  = threadIdx.x;
    const int lane = tid & 63;
    const int wave = tid >> 6;
    const int quad = lane >> 4;
    const int c16  = lane & 15;
    const int n0   = blockIdx.x * 128;
    const int m0   = blockIdx.y * 128;
    const int wm   = (wave >> 1) * 64;
    const int wn   = (wave & 1) * 64;
    const int kchunk = K / S;
    const int kbeg = blockIdx.z * kchunk;

    f32x4_t acc[4][4] = {};

    for (int k0 = kbeg; k0 < kbeg + kchunk; k0 += 32) {
#pragma unroll
        for (int p = 0; p < 2; ++p) {
            const int lin = p * 64 + lane;
            int row = wave * 32 + (lin >> 2);
            int gr  = m0 + row; if (gr > M - 1) gr = M - 1;
            gl_lds16(Abf + (size_t)gr * K + k0 + (lin & 3) * 8, Als + wave * 1024 + p * 512);
        }
#pragma unroll
        for (int p = 0; p < 2; ++p) {
            const int lin = p * 64 + lane;
            const int row = wave * 32 + (lin >> 2);
            gl_lds16(Wt + (size_t)(n0 + row) * K + k0 + (lin & 3) * 8,
                     Bls + wave * 1024 + p * 512);
        }
        __syncthreads();

        bf16x8_t af[4], bfr[4];
#pragma unroll
        for (int i = 0; i < 4; ++i)
            af[i] = *(const bf16x8_t*)(Als + (wm + i * 16 + c16) * 32 + quad * 8);
#pragma unroll
        for (int j = 0; j < 4; ++j)
            bfr[j] = *(const bf16x8_t*)(Bls + (wn + j * 16 + c16) * 32 + quad * 8);
#pragma unroll
        for (int i = 0; i < 4; ++i)
#pragma unroll
            for (int j = 0; j < 4; ++j)
                acc[i][j] = __builtin_amdgcn_mfma_f32_16x16x32_bf16(af[i], bfr[j], acc[i][j], 0, 0, 0);
        __syncthreads();
    }

#pragma unroll
    for (int j = 0; j < 4; ++j) {
        const int col = n0 + wn + j * 16 + c16;
#pragma unroll
        for (int i = 0; i < 4; ++i) {
            const int rowb = m0 + wm + i * 16 + quad * 4;
#pragma unroll
            for (int r = 0; r < 4; ++r) {
                const int row = rowb + r;
                if (row < M) atomicAdd(&Cc[(size_t)row * N + col], acc[i][j][r]);
            }
        }
    }
}

// ---------------------------------------------------------------------------
// MFMA flash attention, direct-global operand feed, K-split S=2.
// 1D grid 960, XCD-swizzled: id = bh + 48*(2*qt + s). Since 48 % 8 == 0,
// id % 8 == bh % 8 — all 20 blocks sharing one (b,h)'s K/V slice (496 KB)
// land on the same XCD under the round-robin block->XCD mapping, so the
// uncoalesced K/V fragment gathers hit that XCD's L2 instead of re-fetching
// from HBM (round-10 FETCH was 97 MB vs 23.8 MB working set). Perf-only.
// ---------------------------------------------------------------------------
__global__ __launch_bounds__(256)
void attn_part_kernel(const __hip_bfloat16* __restrict__ Qb,
                      const __hip_bfloat16* __restrict__ Kb,
                      const __hip_bfloat16* __restrict__ Vtb,
                      const int* __restrict__ cx, const int* __restrict__ cy,
                      const void* __restrict__ bias_x,
                      const void* __restrict__ bias_y,
                      __hip_bfloat16* __restrict__ p0,
                      __hip_bfloat16* __restrict__ p1,
                      float* __restrict__ mlbase,
                      const int* __restrict__ flagp)
{
    constexpr int QT = 64, KT = 64;
    constexpr int QROW = 72;
    __shared__ __hip_bfloat16 Ps[QT * QROW];
    __shared__ float bxs[2 * MAXD + 1], bys[2 * MAXD + 1];

    const int f32  = *flagp;
    const int tid  = threadIdx.x;
    const int lane = tid & 63;
    const int wave = tid >> 6;
    const int quad = lane >> 4;
    const int c16  = lane & 15;

    // XCD-swizzled decode
    const int id   = blockIdx.x;
    const int bh   = id % 48;
    const int rest = id / 48;          // 0..19
    const int s    = rest & 1;
    const int q0   = (rest >> 1) * QT;
    const int b    = bh / NHEAD;
    const int h    = bh - b * NHEAD;
    const int kbeg = s * 1024;
    const int kend = s ? LK : 1024;

    __hip_bfloat16* Op = s ? p1 : p0;
    float* mp = mlbase + (size_t)s * 2 * ML_CNT;
    float* lp = mp + ML_CNT;

    for (int i = tid; i < 2 * MAXD + 1; i += 256) {
        bxs[i] = ldf(bias_x, (size_t)i * NHEAD + h, f32);
        bys[i] = ldf(bias_y, (size_t)i * NHEAD + h, f32);
    }

    // Loop-invariant Q fragments + q coords (direct global, single base)
    const __hip_bfloat16* qrow = Qb + ((size_t)(b * LQ + q0 + wave * 16 + c16)) * DM + h * DK;
    const bf16x8_t aq0 = *(const bf16x8_t*)(qrow + quad * 8);
    const bf16x8_t aq1 = *(const bf16x8_t*)(qrow + 32 + quad * 8);
    int qx[4], qy[4];
#pragma unroll
    for (int r = 0; r < 4; ++r) {
        const int qi = b * LK + LIM + q0 + wave * 16 + quad * 4 + r;
        qx[r] = cx[qi]; qy[r] = cy[qi];
    }
    const __hip_bfloat16* vrow = Vtb + ((size_t)((b * NHEAD + h) * DK)) * LK;

    __syncthreads();   // bias tables visible

    f32x4_t O[4] = {};
    float m_r[4], l_r[4];
#pragma unroll
    for (int r = 0; r < 4; ++r) { m_r[r] = -1e30f; l_r[r] = 0.f; }

    for (int k0 = kbeg; k0 < kend; k0 += KT) {
        // ---- scores: direct-global K fragments ----
        f32x4_t S[4];
#pragma unroll
        for (int jn = 0; jn < 4; ++jn) {
            int krow = k0 + jn * 16 + c16; if (krow > LK - 1) krow = LK - 1;
            const __hip_bfloat16* kr = Kb + ((size_t)(b * LK + krow)) * DM + h * DK;
            bf16x8_t bk0 = *(const bf16x8_t*)(kr + quad * 8);
            bf16x8_t bk1 = *(const bf16x8_t*)(kr + 32 + quad * 8);
            f32x4_t acc = {0.f, 0.f, 0.f, 0.f};
            acc = __builtin_amdgcn_mfma_f32_16x16x32_bf16(aq0, bk0, acc, 0, 0, 0);
            acc = __builtin_amdgcn_mfma_f32_16x16x32_bf16(aq1, bk1, acc, 0, 0, 0);
            S[jn] = acc;
        }
        // ---- bias + tail mask (branch-free single-base coord gather) ----
#pragma unroll
        for (int jn = 0; jn < 4; ++jn) {
            const int kg = k0 + jn * 16 + c16;
            const bool ok = kg < LK;
            const int kgc = ok ? kg : LK - 1;
            const int kx = cx[b * LK + kgc], ky = cy[b * LK + kgc];
#pragma unroll
            for (int r = 0; r < 4; ++r) {
                int rx = min(max(qx[r] - kx, -MAXD), MAXD) + MAXD;
                int ry = min(max(qy[r] - ky, -MAXD), MAXD) + MAXD;
                float v = S[jn][r] + bxs[rx] + bys[ry];
                S[jn][r] = ok ? v : -1e30f;
            }
        }
        // ---- online softmax (registers + shfl over 16-lane row group) ----
        float alpha[4];
#pragma unroll
        for (int r = 0; r < 4; ++r) {
            float mx = fmaxf(fmaxf(S[0][r], S[1][r]), fmaxf(S[2][r], S[3][r]));
            mx = fmaxf(mx, __shfl_xor(mx, 1));
            mx = fmaxf(mx, __shfl_xor(mx, 2));
            mx = fmaxf(mx, __shfl_xor(mx, 4));
            mx = fmaxf(mx, __shfl_xor(mx, 8));
            const float mt = fmaxf(m_r[r], mx);
            const float al = __expf(m_r[r] - mt);
            float sum = 0.f;
#pragma unroll
            for (int jn = 0; jn < 4; ++jn) {
                float p = __expf(S[jn][r] - mt);
                S[jn][r] = p;
                sum += p;
            }
            sum += __shfl_xor(sum, 1);
            sum += __shfl_xor(sum, 2);
            sum += __shfl_xor(sum, 4);
            sum += __shfl_xor(sum, 8);
            m_r[r] = mt;
            l_r[r] = l_r[r] * al + sum;
            alpha[r] = al;
        }
        // ---- P -> LDS (wave-private rows; no barrier) + O rescale ----
#pragma unroll
        for (int jn = 0; jn < 4; ++jn)
#pragma unroll
            for (int r = 0; r < 4; ++r)
                Ps[(wave * 16 + quad * 4 + r) * QROW + jn * 16 + c16] = __float2bfloat16(S[jn][r]);
#pragma unroll
        for (int jd = 0; jd < 4; ++jd)
#pragma unroll
            for (int r = 0; r < 4; ++r) O[jd][r] *= alpha[r];
        // ---- PV: A from Ps, B direct from transposed V in global ----
        bf16x8_t ap0 = *(const bf16x8_t*)(Ps + (wave * 16 + c16) * QROW + quad * 8);
        bf16x8_t ap1 = *(const bf16x8_t*)(Ps + (wave * 16 + c16) * QROW + 32 + quad * 8);
        int kc0 = k0 + quad * 8;      if (kc0 > LK - 8) kc0 = LK - 8;
        int kc1 = k0 + 32 + quad * 8; if (kc1 > LK - 8) kc1 = LK - 8;
#pragma unroll
        for (int jd = 0; jd < 4; ++jd) {
            const __hip_bfloat16* vr = vrow + (size_t)(jd * 16 + c16) * LK;
            bf16x8_t bv0 = *(const bf16x8_t*)(vr + kc0);
            bf16x8_t bv1 = *(const bf16x8_t*)(vr + kc1);
            O[jd] = __builtin_amdgcn_mfma_f32_16x16x32_bf16(ap0, bv0, O[jd], 0, 0, 0);
            O[jd] = __builtin_amdgcn_mfma_f32_16x16x32_bf16(ap1, bv1, O[jd], 0, 0, 0);
        }
    }

    // Epilogue: unnormalized partial O + (m,l)
#pragma unroll
    for (int r = 0; r < 4; ++r) {
        const int ql = wave * 16 + quad * 4 + r;
        const size_t grow = (size_t)(b * LQ + q0 + ql);
#pragma unroll
        for (int jd = 0; jd < 4; ++jd)
            Op[grow * DM + h * DK + jd * 16 + c16] = __float2bfloat16(O[jd][r]);
        if (c16 == 0) {
            size_t mli = ((size_t)b * NHEAD + h) * LQ + q0 + ql;
            mp[mli] = m_r[r];
            lp[mli] = l_r[r];
        }
    }
}

// Merge the two K-splits into ctx (in-place over p0) and zero aof.
__global__ __launch_bounds__(256)
void attn_merge_kernel(const __hip_bfloat16* __restrict__ p0,
                       const __hip_bfloat16* __restrict__ p1,
                       const float* __restrict__ mlbase,
                       __hip_bfloat16* __restrict__ ctx,
                       float* __restrict__ aof)
{
    const int row = blockIdx.x;            // (b,q) flat
    const int b = row / LQ, q = row - b * LQ;
    const int tid = threadIdx.x;
#pragma unroll
    for (int i = 0; i < 3; ++i) {
        const int c = tid + i * 256;
        const int h = c >> 6;
        const size_t mli = ((size_t)b * NHEAD + h) * LQ + q;
        const float m0 = mlbase[mli],              l0 = mlbase[ML_CNT + mli];
        const float m1 = mlbase[2 * ML_CNT + mli], l1 = mlbase[3 * ML_CNT + mli];
        const float mm = fmaxf(m0, m1);
        const float w0 = __expf(m0 - mm), w1 = __expf(m1 - mm);
        const float denom = l0 * w0 + l1 * w1;
        const size_t idx = (size_t)row * DM + c;
        const float v = (b2f(p0[idx]) * w0 + b2f(p1[idx]) * w1) / denom;
        ctx[idx] = __float2bfloat16(v);
        aof[idx] = 0.f;
    }
}

// ---------------------------------------------------------------------------
// LayerNorm over 768 with folded bias: x = A + F32acc + bias2.
//  MODE 0: A = flagged Xin -> bf16 ws out; also zeroes zbuf (next accumulator).
//  MODE 1: A = bf16 Xb     -> flagged-dtype d_out.
// ---------------------------------------------------------------------------
template<int MODE>
__global__ __launch_bounds__(256)
void ln_kernel(const void* __restrict__ Xin,
               const __hip_bfloat16* __restrict__ Xb,
               const float* __restrict__ Xf2f,
               const void* __restrict__ bias2,
               const void* __restrict__ g,
               const void* __restrict__ be,
               __hip_bfloat16* __restrict__ outb,
               void* __restrict__ outv,
               float* __restrict__ zbuf,
               const int* __restrict__ flagp)
{
    __shared__ float red1[256], red2[256];
    const int f32 = *flagp;
    const int row = blockIdx.x;
    const int tid = threadIdx.x;

    float x[3];
#pragma unroll
    for (int i = 0; i < 3; ++i) {
        int c = tid + i * 256;
        size_t idx = (size_t)row * DM + c;
        float a  = (MODE == 0) ? ldf(Xin, idx, f32) : b2f(Xb[idx]);
        x[i] = a + Xf2f[idx] + ldf(bias2, c, f32);
    }
    float s1 = x[0] + x[1] + x[2];
    float s2 = x[0] * x[0] + x[1] * x[1] + x[2] * x[2];
    red1[tid] = s1;
    red2[tid] = s2;
    __syncthreads();
    for (int off = 128; off > 0; off >>= 1) {
        if (tid < off) {
            red1[tid] += red1[tid + off];
            red2[tid] += red2[tid + off];
        }
        __syncthreads();
    }
    float mu   = red1[0] * (1.f / DM);
    float var  = red2[0] * (1.f / DM) - mu * mu;
    float rstd = rsqrtf(var + 1e-5f);
#pragma unroll
    for (int i = 0; i < 3; ++i) {
        int c = tid + i * 256;
        size_t idx = (size_t)row * DM + c;
        float v = (x[i] - mu) * rstd * ldf(g, c, f32) + ldf(be, c, f32);
        if (MODE == 0) {
            outb[idx] = __float2bfloat16(v);
            zbuf[idx] = 0.f;
        } else {
            if (f32) ((float*)outv)[idx] = v;
            else     ((__hip_bfloat16*)outv)[idx] = __float2bfloat16(v);
        }
    }
}

// ---------------------------------------------------------------------------
extern "C" void kernel_launch(void* const* d_in, const int* in_sizes, int n_in,
                              void* d_out, int out_size, void* d_ws, size_t ws_size,
                              hipStream_t stream)
{
    const void* docqa = d_in[0];
    const void* im    = d_in[1];
    const int* dqx = (const int*)d_in[2];
    const int* dqy = (const int*)d_in[3];
    const int* imx = (const int*)d_in[4];
    const int* imy = (const int*)d_in[5];
    const void* Wq = d_in[6];
    const void* bq = d_in[7];
    const void* Wk = d_in[8];
    const void* bk = d_in[9];
    const void* Wv = d_in[10];
    const void* bv = d_in[11];
    const void* Wo = d_in[12];
    const void* bo = d_in[13];
    const void* bias_x = d_in[14];
    const void* bias_y = d_in[15];
    const void* W1 = d_in[16];
    const void* b1 = d_in[17];
    const void* W2 = d_in[18];
    const void* b2 = d_in[19];
    const void* g1  = d_in[20];
    const void* be1 = d_in[21];
    const void* g2  = d_in[22];
    const void* be2 = d_in[23];

    // Workspace pool: 39.6 MB, proven since round 3 (DO NOT GROW).
    //   flag @0; R1 3.93M; R2 11.89M; R3 11.89M; R4 11.89M   [bytes]
    // R1: Wt3 [0,3.54M) (dead after qkv) + cx/cy [3.54M,3.60M) (dead after attn)
    //     -> WtO [0,1.18M) (dead after skWo) -> first part of mid
    // R2 (kb): k row-major -> rest of mid (R1+R2 contiguous, 15.73<=15.82)
    // R3 (vtb): V^T -> aof f32 (7.86M) -> W1t[0,4.72M)+W2t[4.72,9.44M)
    // R4 (cb): fullA bf16 (dead after qkv)
    //          -> p0[0,3.93M) -> ctx -> src1; p1[3.93,7.86M); ml[7.86,8.36M)
    //          -> fof f32 [3.93,11.79M) (zeroed in LN1 after p1/ml die)
    // q lives in d_out (LN2 overwrites d_out at the end).
    char* w = (char*)d_ws;
    int*            flagp = (int*)w;
    __hip_bfloat16* qR  = (__hip_bfloat16*)(w + 256);
    __hip_bfloat16* kb  = qR + (size_t)M_DOC  * DM;
    __hip_bfloat16* vtb = kb + (size_t)M_FULL * DM;
    __hip_bfloat16* cb  = vtb + (size_t)M_FULL * DM;
    char* cbB = (char*)cb;
    char* r1B = (char*)qR;

    __hip_bfloat16* fullA = cb;
    __hip_bfloat16* Wt3  = qR;
    int*            cxp  = (int*)(r1B + 3538944);     // R1 spare tail
    int*            cyp  = cxp + (size_t)B * LK;
    __hip_bfloat16* WtO  = qR;
    __hip_bfloat16* qout = (__hip_bfloat16*)d_out;
    __hip_bfloat16* p0   = cb;
    __hip_bfloat16* p1   = (__hip_bfloat16*)(cbB + 3932160);
    float*          mlb  = (float*)(cbB + 7864320);
    __hip_bfloat16* ctx  = cb;
    __hip_bfloat16* src1 = cb;
    float*          fof  = (float*)(cbB + 3932160);
    float*          aof  = (float*)vtb;
    __hip_bfloat16* W1t  = vtb;
    __hip_bfloat16* W2t  = vtb + (size_t)DFF * DM;
    __hip_bfloat16* mid  = qR;

    dim3 blk(256);

    // flag + fullA bf16 conversion + fused coord arrays
    prep_conv_kernel<<<dim3((M_FULL * (DM / 8) + 255) / 256), blk, 0, stream>>>(
        g1, flagp, im, docqa, dqx, dqy, imx, imy, fullA, cxp, cyp);
    // Wq/Wk/Wv transposes -> Wt3 (in R1)
    wtrans3_kernel<<<dim3(3 * 576), blk, 0, stream>>>(Wq, Wk, Wv, Wt3, flagp);
    // fused q/k/v projection (m97 A-path from fullA; q -> d_out scratch)
    qkv_gemm<<<dim3(3 * DM / 128, (M_FULL + 127) / 128), blk, 0, stream>>>(
        fullA, Wt3, bq, bk, bv, qout, kb, vtb, flagp);
    // attention, K-split S=2, XCD-swizzled 1D grid
    attn_part_kernel<<<dim3(48 * 20), blk, 0, stream>>>(
        qout, kb, vtb, cxp, cyp, bias_x, bias_y, p0, p1, mlb, flagp);
    // merge partials -> ctx; zero aof (V^T dead)
    attn_merge_kernel<<<dim3(M_DOC), blk, 0, stream>>>(p0, p1, mlb, ctx, aof);
    // Wo transpose over dead Wt3
    wtransO_kernel<<<dim3(576), blk, 0, stream>>>(Wo, WtO, flagp);
    // attn_out: split-K S=4 atomics into aof. bo folded into LN1.
    sk_gemm<<<dim3(DM / 128, M_DOC / 128, 4), blk, 0, stream>>>(
        ctx, WtO, aof, M_DOC, DM, DM, 4);
    // src1 = LN(docqa + aof + bo); also zero fof
    ln_kernel<0><<<dim3(M_DOC), blk, 0, stream>>>(
        docqa, nullptr, aof, bo, g1, be1, src1, nullptr, fof, flagp);
    // FFN weight transposes (over dead aof region)
    wtransW_kernel<<<dim3(2 * 2304), blk, 0, stream>>>(W1, W2, W1t, W2t, flagp);
    // mid = relu(src1 @ W1 + b1) -> R1+R2 (WtO/cx/cy dead)
    mfma_gemm_relu<<<dim3(DFF / 128, M_DOC / 128), blk, 0, stream>>>(
        src1, W1t, b1, mid, flagp, M_DOC, DFF, DM);
    // ffn: split-K S=4 atomics into fof. b2 folded into LN2.
    sk_gemm<<<dim3(DM / 128, M_DOC / 128, 4), blk, 0, stream>>>(
        mid, W2t, fof, M_DOC, DM, DFF, 4);
    // out = LN(src1 + fof + b2) -> d_out (overwrites q scratch)
    ln_kernel<1><<<dim3(M_DOC), blk, 0, stream>>>(
        nullptr, src1, fof, b2, g2, be2, nullptr, d_out, nullptr, flagp);
}

// Round 12
// 402.304 us; speedup vs baseline: 1.2029x; 1.0449x over previous
//
#include <hip/hip_runtime.h>
#include <hip/hip_bf16.h>

// Problem constants
constexpr int B      = 4;
constexpr int LQ     = 640;
constexpr int LIM    = 1296;
constexpr int LK     = LQ + LIM;   // 1936
constexpr int DM     = 768;
constexpr int NHEAD  = 12;
constexpr int DK     = 64;
constexpr int DFF    = 3072;
constexpr int MAXD   = 100;
constexpr int M_DOC  = B * LQ;     // 2560
constexpr int M_FULL = B * LK;     // 7744
constexpr size_t ML_CNT = (size_t)B * NHEAD * LQ;   // 30720 (m,l) rows per split

typedef __attribute__((ext_vector_type(8))) short bf16x8_t;   // 8 bf16 = 4 VGPRs
typedef __attribute__((ext_vector_type(4))) float f32x4_t;    // MFMA C/D

__device__ __forceinline__ float b2f(__hip_bfloat16 x) { return __bfloat162float(x); }

__device__ __forceinline__ float ldf(const void* p, size_t i, int f32flag) {
    return f32flag ? ((const float*)p)[i]
                   : b2f(((const __hip_bfloat16*)p)[i]);
}

// async global->LDS, 16 bytes per lane. LDS dest = wave-uniform base + lane*16.
__device__ __forceinline__ void gl_lds16(const void* g, void* l) {
    __builtin_amdgcn_global_load_lds(
        (const __attribute__((address_space(1))) unsigned int*)g,
        (__attribute__((address_space(3))) unsigned int*)l, 16, 0, 0);
}

// ---------------------------------------------------------------------------
// prep: dtype flag + concat(im,docqa) -> contiguous bf16 fullA + fused
// branch-free coordinate arrays cx/cy[b][LK] (round-9 lesson: divergent-base
// gathers in the attention K-loop defeat compiler latency hiding).
// ---------------------------------------------------------------------------
__global__ __launch_bounds__(256)
void prep_conv_kernel(const void* __restrict__ g1, int* __restrict__ flagp,
                      const void* __restrict__ im, const void* __restrict__ docqa,
                      const int* __restrict__ dqx, const int* __restrict__ dqy,
                      const int* __restrict__ imx, const int* __restrict__ imy,
                      __hip_bfloat16* __restrict__ fullA,
                      int* __restrict__ cx, int* __restrict__ cy)
{
    const bool f32 = ((*(const unsigned*)g1) & 0xFFFFu) == 0u;
    if (blockIdx.x == 0 && threadIdx.x == 0) *flagp = f32 ? 1 : 0;

    const int gid = blockIdx.x * 256 + threadIdx.x;
    if (gid < B * LK) {
        int b = gid / LK, l = gid - b * LK;
        cx[gid] = (l < LIM) ? imx[b * LIM + l] : dqx[b * LQ + l - LIM];
        cy[gid] = (l < LIM) ? imy[b * LIM + l] : dqy[b * LQ + l - LIM];
    }

    if (gid >= M_FULL * (DM / 8)) return;
    const int row = gid / (DM / 8);
    const int col = (gid - row * (DM / 8)) * 8;
    const int b   = row / LK;
    const int l   = row - b * LK;
    const size_t srow = (l < LIM) ? ((size_t)(b * LIM + l)) * DM
                                  : ((size_t)(b * LQ + (l - LIM))) * DM;
    const void* src = (l < LIM) ? im : docqa;
    union { bf16x8_t v; __hip_bfloat16 h[8]; } pk;
    if (f32) {
        const float4* fp = (const float4*)((const float*)src + srow + col);
        float4 a = fp[0], c = fp[1];
        pk.h[0] = __float2bfloat16(a.x); pk.h[1] = __float2bfloat16(a.y);
        pk.h[2] = __float2bfloat16(a.z); pk.h[3] = __float2bfloat16(a.w);
        pk.h[4] = __float2bfloat16(c.x); pk.h[5] = __float2bfloat16(c.y);
        pk.h[6] = __float2bfloat16(c.z); pk.h[7] = __float2bfloat16(c.w);
    } else {
        pk.v = *(const bf16x8_t*)((const __hip_bfloat16*)src + srow + col);
    }
    *(bf16x8_t*)(fullA + (size_t)row * DM + col) = pk.v;
}

// ---------------------------------------------------------------------------
// Transpose 32x32 tile helper (K x N flagged -> N x K bf16).
// ---------------------------------------------------------------------------
__device__ __forceinline__ void wtrans_tile(const void* W, __hip_bfloat16* Wt,
                                            int f32, int K, int N, int n0, int k0,
                                            __hip_bfloat16 (*t)[33])
{
    const int tx = threadIdx.x & 31, ty = threadIdx.x >> 5;
#pragma unroll
    for (int j = 0; j < 4; ++j) {
        int k = ty + j * 8;
        t[k][tx] = __float2bfloat16(ldf(W, (size_t)(k0 + k) * N + n0 + tx, f32));
    }
    __syncthreads();
#pragma unroll
    for (int j = 0; j < 4; ++j) {
        int n = ty + j * 8;
        Wt[(size_t)(n0 + n) * K + k0 + tx] = t[tx][n];
    }
}

// Wq,Wk,Wv -> Wt3 (2304 x 768). 3*576 blocks.
__global__ __launch_bounds__(256)
void wtrans3_kernel(const void* __restrict__ Wq, const void* __restrict__ Wk,
                    const void* __restrict__ Wv, __hip_bfloat16* __restrict__ Wt3,
                    const int* __restrict__ flagp)
{
    __shared__ __hip_bfloat16 t[32][33];
    const int f32 = *flagp;
    const int wid = blockIdx.x / 576;
    const int tt  = blockIdx.x % 576;
    const void* W = (wid == 0) ? Wq : (wid == 1) ? Wk : Wv;
    wtrans_tile(W, Wt3 + (size_t)wid * DM * DM, f32, DM, DM,
                (tt % 24) * 32, (tt / 24) * 32, t);
}

// Wo -> WtO. 576 blocks.
__global__ __launch_bounds__(256)
void wtransO_kernel(const void* __restrict__ Wo, __hip_bfloat16* __restrict__ WtO,
                    const int* __restrict__ flagp)
{
    __shared__ __hip_bfloat16 t[32][33];
    const int f32 = *flagp;
    const int tt  = blockIdx.x;
    wtrans_tile(Wo, WtO, f32, DM, DM, (tt % 24) * 32, (tt / 24) * 32, t);
}

// W1 (768x3072) -> W1t, W2 (3072x768) -> W2t. 2*2304 blocks.
__global__ __launch_bounds__(256)
void wtransW_kernel(const void* __restrict__ W1, const void* __restrict__ W2,
                    __hip_bfloat16* __restrict__ W1t, __hip_bfloat16* __restrict__ W2t,
                    const int* __restrict__ flagp)
{
    __shared__ __hip_bfloat16 t[32][33];
    const int f32 = *flagp;
    int bx = blockIdx.x;
    const bool second = bx >= 2304;
    const void* W = second ? W2 : W1;
    __hip_bfloat16* dst = second ? W2t : W1t;
    const int K = second ? DFF : DM;
    const int N = second ? DM : DFF;
    const int tt = second ? bx - 2304 : bx;
    const int nt = N / 32;
    wtrans_tile(W, dst, f32, K, N, (tt % nt) * 32, (tt / nt) * 32, t);
}

// ---------------------------------------------------------------------------
// Fused QKV GEMM, pure m97 structure: A = fullA bf16 via global_load_lds.
// q (doc rows, *1/8) -> qout (d_out scratch); k row-major; V transposed
// per (b,h): vtb[((b*NHEAD+h)*DK + d) * LK + kk].
// ---------------------------------------------------------------------------
__global__ __launch_bounds__(256)
void qkv_gemm(const __hip_bfloat16* __restrict__ fullA,
              const __hip_bfloat16* __restrict__ Wt3,
              const void* __restrict__ bq,
              const void* __restrict__ bk,
              const void* __restrict__ bv,
              __hip_bfloat16* __restrict__ qout,
              __hip_bfloat16* __restrict__ kb,
              __hip_bfloat16* __restrict__ vtb,
              const int* __restrict__ flagp)
{
    __shared__ __hip_bfloat16 Als[128 * 32];
    __shared__ __hip_bfloat16 Bls[128 * 32];

    const int f32  = *flagp;
    const int tid  = threadIdx.x;
    const int lane = tid & 63;
    const int wave = tid >> 6;
    const int quad = lane >> 4;
    const int c16  = lane & 15;
    const int n0   = blockIdx.x * 128;
    const int m0   = blockIdx.y * 128;
    const int wm   = (wave >> 1) * 64;
    const int wn   = (wave & 1) * 64;
    constexpr int K = DM;

    f32x4_t acc[4][4] = {};

    for (int k0 = 0; k0 < K; k0 += 32) {
#pragma unroll
        for (int p = 0; p < 2; ++p) {
            const int lin = p * 64 + lane;
            int row = wave * 32 + (lin >> 2);
            int gr  = m0 + row; if (gr > M_FULL - 1) gr = M_FULL - 1;
            gl_lds16(fullA + (size_t)gr * K + k0 + (lin & 3) * 8,
                     Als + wave * 1024 + p * 512);
        }
#pragma unroll
        for (int p = 0; p < 2; ++p) {
            const int lin = p * 64 + lane;
            const int row = wave * 32 + (lin >> 2);
            gl_lds16(Wt3 + (size_t)(n0 + row) * K + k0 + (lin & 3) * 8,
                     Bls + wave * 1024 + p * 512);
        }
        __syncthreads();

        bf16x8_t af[4], bfr[4];
#pragma unroll
        for (int i = 0; i < 4; ++i)
            af[i] = *(const bf16x8_t*)(Als + (wm + i * 16 + c16) * 32 + quad * 8);
#pragma unroll
        for (int j = 0; j < 4; ++j)
            bfr[j] = *(const bf16x8_t*)(Bls + (wn + j * 16 + c16) * 32 + quad * 8);
#pragma unroll
        for (int i = 0; i < 4; ++i)
#pragma unroll
            for (int j = 0; j < 4; ++j)
                acc[i][j] = __builtin_amdgcn_mfma_f32_16x16x32_bf16(af[i], bfr[j], acc[i][j], 0, 0, 0);
        __syncthreads();
    }

    const int seg = n0 / DM;                 // 0=q 1=k 2=v
    const void* bptr = (seg == 0) ? bq : (seg == 1) ? bk : bv;
#pragma unroll
    for (int j = 0; j < 4; ++j) {
        const int col  = n0 + wn + j * 16 + c16;
        const int ncol = col - seg * DM;
        const float bj = ldf(bptr, ncol, f32);
        if (seg == 2) {
            // V transposed: vtb[((bb*NHEAD+h)*DK+d)*LK + kk]
            const int h = ncol >> 6, d = ncol & 63;
#pragma unroll
            for (int i = 0; i < 4; ++i) {
                const int rowb = m0 + wm + i * 16 + quad * 4;
                const int bb0  = rowb / LK;
                const int l0   = rowb - bb0 * LK;
                if (l0 + 3 < LK && rowb + 3 < M_FULL) {
                    union { ushort4 u4; __hip_bfloat16 hh[4]; } pk;
#pragma unroll
                    for (int r = 0; r < 4; ++r)
                        pk.hh[r] = __float2bfloat16(acc[i][j][r] + bj);
                    *(ushort4*)(vtb + ((size_t)((bb0 * NHEAD + h) * DK + d)) * LK + l0) = pk.u4;
                } else {
#pragma unroll
                    for (int r = 0; r < 4; ++r) {
                        const int row = rowb + r;
                        if (row < M_FULL) {
                            int bb = row / LK, l = row - bb * LK;
                            vtb[((size_t)((bb * NHEAD + h) * DK + d)) * LK + l] =
                                __float2bfloat16(acc[i][j][r] + bj);
                        }
                    }
                }
            }
        } else {
            const float scl = (seg == 0) ? 0.125f : 1.f;
#pragma unroll
            for (int i = 0; i < 4; ++i) {
                const int rowb = m0 + wm + i * 16 + quad * 4;
#pragma unroll
                for (int r = 0; r < 4; ++r) {
                    const int row = rowb + r;
                    if (row < M_FULL) {
                        __hip_bfloat16 hv = __float2bfloat16((acc[i][j][r] + bj) * scl);
                        if (seg == 1) kb[(size_t)row * DM + ncol] = hv;
                        else {
                            int bb = row / LK, l = row - bb * LK;
                            if (l >= LIM)
                                qout[(size_t)(bb * LQ + (l - LIM)) * DM + ncol] = hv;
                        }
                    }
                }
            }
        }
    }
}

// Standard MFMA GEMM (bias + relu) for FFN1.
__global__ __launch_bounds__(256)
void mfma_gemm_relu(const __hip_bfloat16* __restrict__ Abf,
                    const __hip_bfloat16* __restrict__ Wt,
                    const void* __restrict__ bias,
                    __hip_bfloat16* __restrict__ Cc,
                    const int* __restrict__ flagp,
                    int M, int N, int K)
{
    __shared__ __hip_bfloat16 Als[128 * 32];
    __shared__ __hip_bfloat16 Bls[128 * 32];

    const int f32  = *flagp;
    const int tid  = threadIdx.x;
    const int lane = tid & 63;
    const int wave = tid >> 6;
    const int quad = lane >> 4;
    const int c16  = lane & 15;
    const int n0   = blockIdx.x * 128;
    const int m0   = blockIdx.y * 128;
    const int wm   = (wave >> 1) * 64;
    const int wn   = (wave & 1) * 64;

    f32x4_t acc[4][4] = {};

    for (int k0 = 0; k0 < K; k0 += 32) {
#pragma unroll
        for (int p = 0; p < 2; ++p) {
            const int lin = p * 64 + lane;
            int row = wave * 32 + (lin >> 2);
            int gr  = m0 + row; if (gr > M - 1) gr = M - 1;
            gl_lds16(Abf + (size_t)gr * K + k0 + (lin & 3) * 8, Als + wave * 1024 + p * 512);
        }
#pragma unroll
        for (int p = 0; p < 2; ++p) {
            const int lin = p * 64 + lane;
            const int row = wave * 32 + (lin >> 2);
            gl_lds16(Wt + (size_t)(n0 + row) * K + k0 + (lin & 3) * 8,
                     Bls + wave * 1024 + p * 512);
        }
        __syncthreads();

        bf16x8_t af[4], bfr[4];
#pragma unroll
        for (int i = 0; i < 4; ++i)
            af[i] = *(const bf16x8_t*)(Als + (wm + i * 16 + c16) * 32 + quad * 8);
#pragma unroll
        for (int j = 0; j < 4; ++j)
            bfr[j] = *(const bf16x8_t*)(Bls + (wn + j * 16 + c16) * 32 + quad * 8);
#pragma unroll
        for (int i = 0; i < 4; ++i)
#pragma unroll
            for (int j = 0; j < 4; ++j)
                acc[i][j] = __builtin_amdgcn_mfma_f32_16x16x32_bf16(af[i], bfr[j], acc[i][j], 0, 0, 0);
        __syncthreads();
    }

#pragma unroll
    for (int j = 0; j < 4; ++j) {
        const int col = n0 + wn + j * 16 + c16;
        const float bj = ldf(bias, col, f32);
#pragma unroll
        for (int i = 0; i < 4; ++i) {
            const int rowb = m0 + wm + i * 16 + quad * 4;
#pragma unroll
            for (int r = 0; r < 4; ++r) {
                const int row = rowb + r;
                if (row < M) {
                    float v = fmaxf(acc[i][j][r] + bj, 0.f);
                    Cc[(size_t)row * N + col] = __float2bfloat16(v);
                }
            }
        }
    }
}

// Split-K MFMA GEMM: f32 atomic accumulate (dest pre-zeroed), grid z = chunk.
__global__ __launch_bounds__(256)
void sk_gemm(const __hip_bfloat16* __restrict__ Abf,
             const __hip_bfloat16* __restrict__ Wt,
             float* __restrict__ Cc,
             int M, int N, int K, int S)
{
    __shared__ __hip_bfloat16 Als[128 * 32];
    __shared__ __hip_bfloat16 Bls[128 * 32];

    const int tid  = threadIdx.x;
    const int lane = tid & 63;
    const int wave = tid >> 6;
    const int quad = lane >> 4;
    const int c16  = lane & 15;
    const int n0   = blockIdx.x * 128;
    const int m0   = blockIdx.y * 128;
    const int wm   = (wave >> 1) * 64;
    const int wn   = (wave & 1) * 64;
    const int kchunk = K / S;
    const int kbeg = blockIdx.z * kchunk;

    f32x4_t acc[4][4] = {};

    for (int k0 = kbeg; k0 < kbeg + kchunk; k0 += 32) {
#pragma unroll
        for (int p = 0; p < 2; ++p) {
            const int lin = p * 64 + lane;
            int row = wave * 32 + (lin >> 2);
            int gr  = m0 + row; if (gr > M - 1) gr = M - 1;
            gl_lds16(Abf + (size_t)gr * K + k0 + (lin & 3) * 8, Als + wave * 1024 + p * 512);
        }
#pragma unroll
        for (int p = 0; p < 2; ++p) {
            const int lin = p * 64 + lane;
            const int row = wave * 32 + (lin >> 2);
            gl_lds16(Wt + (size_t)(n0 + row) * K + k0 + (lin & 3) * 8,
                     Bls + wave * 1024 + p * 512);
        }
        __syncthreads();

        bf16x8_t af[4], bfr[4];
#pragma unroll
        for (int i = 0; i < 4; ++i)
            af[i] = *(const bf16x8_t*)(Als + (wm + i * 16 + c16) * 32 + quad * 8);
#pragma unroll
        for (int j = 0; j < 4; ++j)
            bfr[j] = *(const bf16x8_t*)(Bls + (wn + j * 16 + c16) * 32 + quad * 8);
#pragma unroll
        for (int i = 0; i < 4; ++i)
#pragma unroll
            for (int j = 0; j < 4; ++j)
                acc[i][j] = __builtin_amdgcn_mfma_f32_16x16x32_bf16(af[i], bfr[j], acc[i][j], 0, 0, 0);
        __syncthreads();
    }

#pragma unroll
    for (int j = 0; j < 4; ++j) {
        const int col = n0 + wn + j * 16 + c16;
#pragma unroll
        for (int i = 0; i < 4; ++i) {
            const int rowb = m0 + wm + i * 16 + quad * 4;
#pragma unroll
            for (int r = 0; r < 4; ++r) {
                const int row = rowb + r;
                if (row < M) atomicAdd(&Cc[(size_t)row * N + col], acc[i][j][r]);
            }
        }
    }
}

// ---------------------------------------------------------------------------
// MFMA flash attention v2: K/V/Q staged into LDS via coalesced global_load_lds
// (fetched ONCE per block — round-11 analysis: each wave redundantly gathering
// the full K/V tile saturated the per-CU vector-memory/L2 request pipe at
// ~1030 cyc/wave-tile). Linear lane->LDS placement is mandatory (m104/m108),
// so an XOR chunk swizzle (chunk' = chunk ^ (row&7)) is applied on the GLOBAL
// address side: same 64B segments (coalescing preserved), and b128 fragment
// reads land 2-way bank-aliased (free, m136) instead of 16-way.
// K-split S=2, 1D XCD-swizzled grid (id%8 == bh%8). Register online softmax.
// ---------------------------------------------------------------------------
__global__ __launch_bounds__(256)
void attn_part_kernel(const __hip_bfloat16* __restrict__ Qb,
                      const __hip_bfloat16* __restrict__ Kb,
                      const __hip_bfloat16* __restrict__ Vtb,
                      const int* __restrict__ cx, const int* __restrict__ cy,
                      const void* __restrict__ bias_x,
                      const void* __restrict__ bias_y,
                      __hip_bfloat16* __restrict__ p0,
                      __hip_bfloat16* __restrict__ p1,
                      float* __restrict__ mlbase,
                      const int* __restrict__ flagp)
{
    constexpr int QT = 64, KT = 64;
    constexpr int QROW = 72;
    __shared__ __hip_bfloat16 Qs[QT * DK];     // 8 KB, swizzled [row][chunk^row&7]
    __shared__ __hip_bfloat16 Ks[KT * DK];     // 8 KB
    __shared__ __hip_bfloat16 Vs[DK * KT];     // 8 KB ([d][kk])
    __shared__ __hip_bfloat16 Ps[QT * QROW];   // wave-private rows
    __shared__ float bxs[2 * MAXD + 1], bys[2 * MAXD + 1];

    const int f32  = *flagp;
    const int tid  = threadIdx.x;
    const int lane = tid & 63;
    const int wave = tid >> 6;
    const int quad = lane >> 4;
    const int c16  = lane & 15;

    // XCD-swizzled decode
    const int id   = blockIdx.x;
    const int bh   = id % 48;
    const int rest = id / 48;          // 0..19
    const int s    = rest & 1;
    const int q0   = (rest >> 1) * QT;
    const int b    = bh / NHEAD;
    const int h    = bh - b * NHEAD;
    const int kbeg = s * 1024;
    const int kend = s ? LK : 1024;

    __hip_bfloat16* Op = s ? p1 : p0;
    float* mp = mlbase + (size_t)s * 2 * ML_CNT;
    float* lp = mp + ML_CNT;

    for (int i = tid; i < 2 * MAXD + 1; i += 256) {
        bxs[i] = ldf(bias_x, (size_t)i * NHEAD + h, f32);
        bys[i] = ldf(bias_y, (size_t)i * NHEAD + h, f32);
    }

    const __hip_bfloat16* kbase = Kb + ((size_t)(b * LK)) * DM + h * DK;
    const __hip_bfloat16* vbase = Vtb + ((size_t)((b * NHEAD + h) * DK)) * LK;
    const __hip_bfloat16* qbase = Qb + ((size_t)(b * LQ + q0)) * DM + h * DK;

    // ---- stage Q once (swizzled chunks; wave stages its own 16 rows) ----
    {
        const int rsub = lane >> 3;            // 0..7
        const int cg0  = (lane & 7) ^ (rsub & 7);
#pragma unroll
        for (int p = 0; p < 2; ++p) {
            const int rl = wave * 16 + p * 8 + rsub;
            gl_lds16(qbase + (size_t)rl * DM + cg0 * 8, Qs + (wave * 16 + p * 8) * DK);
        }
    }

    int qx[4], qy[4];
#pragma unroll
    for (int r = 0; r < 4; ++r) {
        const int qi = b * LK + LIM + q0 + wave * 16 + quad * 4 + r;
        qx[r] = cx[qi]; qy[r] = cy[qi];
    }

    __syncthreads();   // Qs + bias visible

    // loop-invariant Q fragments from swizzled LDS
    const int sw  = c16 & 7;
    const int cA0 = (quad ^ sw) * 8;
    const int cA1 = ((quad + 4) ^ sw) * 8;
    const int rQ  = wave * 16 + c16;
    const bf16x8_t aq0 = *(const bf16x8_t*)(Qs + rQ * DK + cA0);
    const bf16x8_t aq1 = *(const bf16x8_t*)(Qs + rQ * DK + cA1);

    f32x4_t O[4] = {};
    float m_r[4], l_r[4];
#pragma unroll
    for (int r = 0; r < 4; ++r) { m_r[r] = -1e30f; l_r[r] = 0.f; }

    const int rsub = lane >> 3;
    const int cgl  = (lane & 7) ^ (rsub & 7);

    for (int k0 = kbeg; k0 < kend; k0 += KT) {
        // ---- stage K tile + V tile (coalesced, once per block) ----
#pragma unroll
        for (int p = 0; p < 2; ++p) {
            const int rl = wave * 16 + p * 8 + rsub;     // local K row 0..63
            int gr = k0 + rl; if (gr > LK - 1) gr = LK - 1;
            gl_lds16(kbase + (size_t)gr * DM + cgl * 8, Ks + (wave * 16 + p * 8) * DK);
        }
#pragma unroll
        for (int p = 0; p < 2; ++p) {
            const int dl = wave * 16 + p * 8 + rsub;     // d row 0..63
            int kks = k0 + cgl * 8; if (kks > LK - 8) kks = LK - 8;
            gl_lds16(vbase + (size_t)dl * LK + kks, Vs + (wave * 16 + p * 8) * KT);
        }
        __syncthreads();   // staged data visible

        // ---- scores from LDS K fragments ----
        f32x4_t S[4];
#pragma unroll
        for (int jn = 0; jn < 4; ++jn) {
            const int rK = jn * 16 + c16;
            bf16x8_t bk0 = *(const bf16x8_t*)(Ks + rK * DK + cA0);
            bf16x8_t bk1 = *(const bf16x8_t*)(Ks + rK * DK + cA1);
            f32x4_t acc = {0.f, 0.f, 0.f, 0.f};
            acc = __builtin_amdgcn_mfma_f32_16x16x32_bf16(aq0, bk0, acc, 0, 0, 0);
            acc = __builtin_amdgcn_mfma_f32_16x16x32_bf16(aq1, bk1, acc, 0, 0, 0);
            S[jn] = acc;
        }
        // ---- bias + tail mask (branch-free single-base coord gather) ----
#pragma unroll
        for (int jn = 0; jn < 4; ++jn) {
            const int kg = k0 + jn * 16 + c16;
            const bool ok = kg < LK;
            const int kgc = ok ? kg : LK - 1;
            const int kx = cx[b * LK + kgc], ky = cy[b * LK + kgc];
#pragma unroll
            for (int r = 0; r < 4; ++r) {
                int rx = min(max(qx[r] - kx, -MAXD), MAXD) + MAXD;
                int ry = min(max(qy[r] - ky, -MAXD), MAXD) + MAXD;
                float v = S[jn][r] + bxs[rx] + bys[ry];
                S[jn][r] = ok ? v : -1e30f;
            }
        }
        // ---- online softmax (registers + shfl over 16-lane row group) ----
        float alpha[4];
#pragma unroll
        for (int r = 0; r < 4; ++r) {
            float mx = fmaxf(fmaxf(S[0][r], S[1][r]), fmaxf(S[2][r], S[3][r]));
            mx = fmaxf(mx, __shfl_xor(mx, 1));
            mx = fmaxf(mx, __shfl_xor(mx, 2));
            mx = fmaxf(mx, __shfl_xor(mx, 4));
            mx = fmaxf(mx, __shfl_xor(mx, 8));
            const float mt = fmaxf(m_r[r], mx);
            const float al = __expf(m_r[r] - mt);
            float sum = 0.f;
#pragma unroll
            for (int jn = 0; jn < 4; ++jn) {
                float p = __expf(S[jn][r] - mt);
                S[jn][r] = p;
                sum += p;
            }
            sum += __shfl_xor(sum, 1);
            sum += __shfl_xor(sum, 2);
            sum += __shfl_xor(sum, 4);
            sum += __shfl_xor(sum, 8);
            m_r[r] = mt;
            l_r[r] = l_r[r] * al + sum;
            alpha[r] = al;
        }
        // ---- P -> LDS (wave-private rows; no barrier) + O rescale ----
#pragma unroll
        for (int jn = 0; jn < 4; ++jn)
#pragma unroll
            for (int r = 0; r < 4; ++r)
                Ps[(wave * 16 + quad * 4 + r) * QROW + jn * 16 + c16] = __float2bfloat16(S[jn][r]);
#pragma unroll
        for (int jd = 0; jd < 4; ++jd)
#pragma unroll
            for (int r = 0; r < 4; ++r) O[jd][r] *= alpha[r];
        // ---- PV: A from Ps, B from swizzled Vs ----
        bf16x8_t ap0 = *(const bf16x8_t*)(Ps + (wave * 16 + c16) * QROW + quad * 8);
        bf16x8_t ap1 = *(const bf16x8_t*)(Ps + (wave * 16 + c16) * QROW + 32 + quad * 8);
#pragma unroll
        for (int jd = 0; jd < 4; ++jd) {
            const int rV = jd * 16 + c16;
            bf16x8_t bv0 = *(const bf16x8_t*)(Vs + rV * KT + cA0);
            bf16x8_t bv1 = *(const bf16x8_t*)(Vs + rV * KT + cA1);
            O[jd] = __builtin_amdgcn_mfma_f32_16x16x32_bf16(ap0, bv0, O[jd], 0, 0, 0);
            O[jd] = __builtin_amdgcn_mfma_f32_16x16x32_bf16(ap1, bv1, O[jd], 0, 0, 0);
        }
        __syncthreads();   // all waves done with Ks/Vs before next staging
    }

    // Epilogue: unnormalized partial O + (m,l)
#pragma unroll
    for (int r = 0; r < 4; ++r) {
        const int ql = wave * 16 + quad * 4 + r;
        const size_t grow = (size_t)(b * LQ + q0 + ql);
#pragma unroll
        for (int jd = 0; jd < 4; ++jd)
            Op[grow * DM + h * DK + jd * 16 + c16] = __float2bfloat16(O[jd][r]);
        if (c16 == 0) {
            size_t mli = ((size_t)b * NHEAD + h) * LQ + q0 + ql;
            mp[mli] = m_r[r];
            lp[mli] = l_r[r];
        }
    }
}

// Merge the two K-splits into ctx (in-place over p0) and zero aof.
__global__ __launch_bounds__(256)
void attn_merge_kernel(const __hip_bfloat16* __restrict__ p0,
                       const __hip_bfloat16* __restrict__ p1,
                       const float* __restrict__ mlbase,
                       __hip_bfloat16* __restrict__ ctx,
                       float* __restrict__ aof)
{
    const int row = blockIdx.x;            // (b,q) flat
    const int b = row / LQ, q = row - b * LQ;
    const int tid = threadIdx.x;
#pragma unroll
    for (int i = 0; i < 3; ++i) {
        const int c = tid + i * 256;
        const int h = c >> 6;
        const size_t mli = ((size_t)b * NHEAD + h) * LQ + q;
        const float m0 = mlbase[mli],              l0 = mlbase[ML_CNT + mli];
        const float m1 = mlbase[2 * ML_CNT + mli], l1 = mlbase[3 * ML_CNT + mli];
        const float mm = fmaxf(m0, m1);
        const float w0 = __expf(m0 - mm), w1 = __expf(m1 - mm);
        const float denom = l0 * w0 + l1 * w1;
        const size_t idx = (size_t)row * DM + c;
        const float v = (b2f(p0[idx]) * w0 + b2f(p1[idx]) * w1) / denom;
        ctx[idx] = __float2bfloat16(v);
        aof[idx] = 0.f;
    }
}

// ---------------------------------------------------------------------------
// LayerNorm over 768 with folded bias: x = A + F32acc + bias2.
//  MODE 0: A = flagged Xin -> bf16 ws out; also zeroes zbuf (next accumulator).
//  MODE 1: A = bf16 Xb     -> flagged-dtype d_out.
// ---------------------------------------------------------------------------
template<int MODE>
__global__ __launch_bounds__(256)
void ln_kernel(const void* __restrict__ Xin,
               const __hip_bfloat16* __restrict__ Xb,
               const float* __restrict__ Xf2f,
               const void* __restrict__ bias2,
               const void* __restrict__ g,
               const void* __restrict__ be,
               __hip_bfloat16* __restrict__ outb,
               void* __restrict__ outv,
               float* __restrict__ zbuf,
               const int* __restrict__ flagp)
{
    __shared__ float red1[256], red2[256];
    const int f32 = *flagp;
    const int row = blockIdx.x;
    const int tid = threadIdx.x;

    float x[3];
#pragma unroll
    for (int i = 0; i < 3; ++i) {
        int c = tid + i * 256;
        size_t idx = (size_t)row * DM + c;
        float a  = (MODE == 0) ? ldf(Xin, idx, f32) : b2f(Xb[idx]);
        x[i] = a + Xf2f[idx] + ldf(bias2, c, f32);
    }
    float s1 = x[0] + x[1] + x[2];
    float s2 = x[0] * x[0] + x[1] * x[1] + x[2] * x[2];
    red1[tid] = s1;
    red2[tid] = s2;
    __syncthreads();
    for (int off = 128; off > 0; off >>= 1) {
        if (tid < off) {
            red1[tid] += red1[tid + off];
            red2[tid] += red2[tid + off];
        }
        __syncthreads();
    }
    float mu   = red1[0] * (1.f / DM);
    float var  = red2[0] * (1.f / DM) - mu * mu;
    float rstd = rsqrtf(var + 1e-5f);
#pragma unroll
    for (int i = 0; i < 3; ++i) {
        int c = tid + i * 256;
        size_t idx = (size_t)row * DM + c;
        float v = (x[i] - mu) * rstd * ldf(g, c, f32) + ldf(be, c, f32);
        if (MODE == 0) {
            outb[idx] = __float2bfloat16(v);
            zbuf[idx] = 0.f;
        } else {
            if (f32) ((float*)outv)[idx] = v;
            else     ((__hip_bfloat16*)outv)[idx] = __float2bfloat16(v);
        }
    }
}

// ---------------------------------------------------------------------------
extern "C" void kernel_launch(void* const* d_in, const int* in_sizes, int n_in,
                              void* d_out, int out_size, void* d_ws, size_t ws_size,
                              hipStream_t stream)
{
    const void* docqa = d_in[0];
    const void* im    = d_in[1];
    const int* dqx = (const int*)d_in[2];
    const int* dqy = (const int*)d_in[3];
    const int* imx = (const int*)d_in[4];
    const int* imy = (const int*)d_in[5];
    const void* Wq = d_in[6];
    const void* bq = d_in[7];
    const void* Wk = d_in[8];
    const void* bk = d_in[9];
    const void* Wv = d_in[10];
    const void* bv = d_in[11];
    const void* Wo = d_in[12];
    const void* bo = d_in[13];
    const void* bias_x = d_in[14];
    const void* bias_y = d_in[15];
    const void* W1 = d_in[16];
    const void* b1 = d_in[17];
    const void* W2 = d_in[18];
    const void* b2 = d_in[19];
    const void* g1  = d_in[20];
    const void* be1 = d_in[21];
    const void* g2  = d_in[22];
    const void* be2 = d_in[23];

    // Workspace pool: 39.6 MB, proven since round 3 (DO NOT GROW).
    //   flag @0; R1 3.93M; R2 11.89M; R3 11.89M; R4 11.89M   [bytes]
    // R1: Wt3 [0,3.54M) (dead after qkv) + cx/cy [3.54M,3.60M) (dead after attn)
    //     -> WtO [0,1.18M) (dead after skWo) -> first part of mid
    // R2 (kb): k row-major -> rest of mid (R1+R2 contiguous, 15.73<=15.82)
    // R3 (vtb): V^T -> aof f32 (7.86M) -> W1t[0,4.72M)+W2t[4.72,9.44M)
    // R4 (cb): fullA bf16 (dead after qkv)
    //          -> p0[0,3.93M) -> ctx -> src1; p1[3.93,7.86M); ml[7.86,8.36M)
    //          -> fof f32 [3.93,11.79M) (zeroed in LN1 after p1/ml die)
    // q lives in d_out (LN2 overwrites d_out at the end).
    char* w = (char*)d_ws;
    int*            flagp = (int*)w;
    __hip_bfloat16* qR  = (__hip_bfloat16*)(w + 256);
    __hip_bfloat16* kb  = qR + (size_t)M_DOC  * DM;
    __hip_bfloat16* vtb = kb + (size_t)M_FULL * DM;
    __hip_bfloat16* cb  = vtb + (size_t)M_FULL * DM;
    char* cbB = (char*)cb;
    char* r1B = (char*)qR;

    __hip_bfloat16* fullA = cb;
    __hip_bfloat16* Wt3  = qR;
    int*            cxp  = (int*)(r1B + 3538944);     // R1 spare tail
    int*            cyp  = cxp + (size_t)B * LK;
    __hip_bfloat16* WtO  = qR;
    __hip_bfloat16* qout = (__hip_bfloat16*)d_out;
    __hip_bfloat16* p0   = cb;
    __hip_bfloat16* p1   = (__hip_bfloat16*)(cbB + 3932160);
    float*          mlb  = (float*)(cbB + 7864320);
    __hip_bfloat16* ctx  = cb;
    __hip_bfloat16* src1 = cb;
    float*          fof  = (float*)(cbB + 3932160);
    float*          aof  = (float*)vtb;
    __hip_bfloat16* W1t  = vtb;
    __hip_bfloat16* W2t  = vtb + (size_t)DFF * DM;
    __hip_bfloat16* mid  = qR;

    dim3 blk(256);

    // flag + fullA bf16 conversion + fused coord arrays
    prep_conv_kernel<<<dim3((M_FULL * (DM / 8) + 255) / 256), blk, 0, stream>>>(
        g1, flagp, im, docqa, dqx, dqy, imx, imy, fullA, cxp, cyp);
    // Wq/Wk/Wv transposes -> Wt3 (in R1)
    wtrans3_kernel<<<dim3(3 * 576), blk, 0, stream>>>(Wq, Wk, Wv, Wt3, flagp);
    // fused q/k/v projection (m97 A-path from fullA; q -> d_out scratch)
    qkv_gemm<<<dim3(3 * DM / 128, (M_FULL + 127) / 128), blk, 0, stream>>>(
        fullA, Wt3, bq, bk, bv, qout, kb, vtb, flagp);
    // attention, K-split S=2, XCD-swizzled 1D grid, LDS-staged operands
    attn_part_kernel<<<dim3(48 * 20), blk, 0, stream>>>(
        qout, kb, vtb, cxp, cyp, bias_x, bias_y, p0, p1, mlb, flagp);
    // merge partials -> ctx; zero aof (V^T dead)
    attn_merge_kernel<<<dim3(M_DOC), blk, 0, stream>>>(p0, p1, mlb, ctx, aof);
    // Wo transpose over dead Wt3
    wtransO_kernel<<<dim3(576), blk, 0, stream>>>(Wo, WtO, flagp);
    // attn_out: split-K S=4 atomics into aof. bo folded into LN1.
    sk_gemm<<<dim3(DM / 128, M_DOC / 128, 4), blk, 0, stream>>>(
        ctx, WtO, aof, M_DOC, DM, DM, 4);
    // src1 = LN(docqa + aof + bo); also zero fof
    ln_kernel<0><<<dim3(M_DOC), blk, 0, stream>>>(
        docqa, nullptr, aof, bo, g1, be1, src1, nullptr, fof, flagp);
    // FFN weight transposes (over dead aof region)
    wtransW_kernel<<<dim3(2 * 2304), blk, 0, stream>>>(W1, W2, W1t, W2t, flagp);
    // mid = relu(src1 @ W1 + b1) -> R1+R2 (WtO/cx/cy dead)
    mfma_gemm_relu<<<dim3(DFF / 128, M_DOC / 128), blk, 0, stream>>>(
        src1, W1t, b1, mid, flagp, M_DOC, DFF, DM);
    // ffn: split-K S=4 atomics into fof. b2 folded into LN2.
    sk_gemm<<<dim3(DM / 128, M_DOC / 128, 4), blk, 0, stream>>>(
        mid, W2t, fof, M_DOC, DM, DFF, 4);
    // out = LN(src1 + fof + b2) -> d_out (overwrites q scratch)
    ln_kernel<1><<<dim3(M_DOC), blk, 0, stream>>>(
        nullptr, src1, fof, b2, g2, be2, nullptr, d_out, nullptr, flagp);
}